// Round 11
// baseline (23077.344 us; speedup 1.0000x reference)
//
#include <hip/hip_runtime.h>
#include <math.h>

// ---------------------------------------------------------------------------
// Model constants
#define L_ENC 750
#define T_AUD 1500
#define DD    384
#define FF    1024
#define NHH   4
#define HDIM  96
#define VOCAB 60
#define T_TXT 256
#define BB    8
#define NB    480   // persistent decode grid: 2 blocks/CU, co-resident
#define TB    512   // decode block size

static __device__ __forceinline__ float sigmf(float x){ return 1.f/(1.f + __expf(-x)); }

// Coherent (coherence-point) accessors for mutable cross-block state.
static __device__ __forceinline__ float cld(const float* p){
  return __hip_atomic_load(p, __ATOMIC_RELAXED, __HIP_MEMORY_SCOPE_AGENT);
}
static __device__ __forceinline__ void cst(float* p, float v){
  __hip_atomic_store(p, v, __ATOMIC_RELAXED, __HIP_MEMORY_SCOPE_AGENT);
}

// bf16 <-> fp32 (bf16 stored as unsigned short; RNE on pack)
static __device__ __forceinline__ float bf2f(unsigned int v){
  union { unsigned int u; float f; } c; c.u = v << 16; return c.f;
}
static __device__ __forceinline__ unsigned short f2bf(float x){
  union { float f; unsigned int u; } c; c.f = x;
  unsigned int u = c.u + 0x7fffu + ((c.u >> 16) & 1u);
  return (unsigned short)(u >> 16);
}

// ---------------------------------------------------------------------------
// workspace layout (float offsets)
static constexpr size_t O_X  = 0;
static constexpr size_t O_EA = 2304000;
static constexpr size_t O_ED = 4608000;
static constexpr size_t O_ST = 6912000;
static constexpr size_t oHASR = O_ST + 0;        // 6000
static constexpr size_t oATT0 = O_ST + 6000;     // 6000
static constexpr size_t oATT1 = O_ST + 12000;    // 6000
static constexpr size_t oHD   = O_ST + 18000;    // 3072 (in-place GRU)
static constexpr size_t oACTX = O_ST + 21072;    // 3072 (single writer, single buffer)
static constexpr size_t oSCTX = O_ST + 27216;    // 3072
static constexpr size_t oPREP = O_ST + 33360;    // 3072
static constexpr size_t oGIA  = O_ST + 39504;    // 18000
static constexpr size_t oGHA  = O_ST + 57504;    // 18000
static constexpr size_t oGID  = O_ST + 75504;    // 9216
static constexpr size_t oGHD  = O_ST + 84720;    // 9216
static constexpr size_t oLACC = O_ST + 93936;    // 8
static constexpr size_t oVLA  = O_ST + 93944;    // 6000
static constexpr size_t oINVN = O_ST + 99944;    // 64
static constexpr size_t oBAR  = O_ST + 100008;   // 4096 u32 (slots + flags)
static constexpr size_t oZ384 = O_ST + 104200;   // 384 zeros (bias for DIB gemm)
static constexpr size_t O_SCR = O_ST + 105000;
// bf16 packed weights [K/8][NR][8] (sizes in FLOATS = ushorts/2)
static constexpr size_t oWIHAT_A = O_SCR + 0;         // 48*2250*8 us = 432000
static constexpr size_t oWHHT_A  = O_SCR + 432000;    // 94*2250*8 us = 846000
static constexpr size_t oWIHAT_D = O_SCR + 1278000;   // 48*1152*8 us = 221184
static constexpr size_t oWHHT_D  = O_SCR + 1499184;   // 48*1152*8 us = 221184
static constexpr size_t oH2ATh   = O_SCR + 1720368;   // 750*384 us = 144000
static constexpr size_t oAOT     = O_SCR + 1864368;   // 384*60 f
static constexpr size_t oEMBT    = O_SCR + 1887408;   // 2048*384 f
static constexpr size_t oGEA     = O_SCR + 2673840;   // 2048*2250 f
static constexpr size_t oGED     = O_SCR + 7281840;   // 2048*1152 f
static constexpr size_t oDIB     = O_SCR + 9641136;   // 64*384 f
static constexpr size_t oEAh     = O_SCR + 9665712;   // 8*750*384 us = 1152000
static constexpr size_t oEDh     = O_SCR + 10817712;  // 1152000
static constexpr size_t oTMPH    = O_SCR + 12000000;  // 288000 f temp (H2AT fp32)

// ---------------------------------------------------------------------------
// Generic tiled transpose: out[c*R + r] = in[r*ldin + c]
__global__ void transpose_k(const float* __restrict__ in, int ldin, int R, int C,
                            float* __restrict__ out){
  __shared__ float t[32][33];
  int c0 = blockIdx.x*32, r0 = blockIdx.y*32;
  int x = threadIdx.x, y = threadIdx.y;
  for (int i = y; i < 32; i += 8){
    int r = r0 + i, c = c0 + x;
    t[i][x] = (r < R && c < C) ? in[(size_t)r*ldin + c] : 0.f;
  }
  __syncthreads();
  for (int i = y; i < 32; i += 8){
    int c = c0 + i, r = r0 + x;
    if (c < C && r < R) out[(size_t)c*R + r] = t[x][i];
  }
}

// Pack transposed weights bf16 as [K/8][R][8]
__global__ void packTbf_k(const float* __restrict__ in, int ldin, int R, int K,
                          unsigned short* __restrict__ out){
  __shared__ float tl[32][33];
  int k0 = blockIdx.x*32, r0 = blockIdx.y*32;
  int x = threadIdx.x, y = threadIdx.y;
  int K8 = ((K + 7) >> 3) << 3;
  for (int i = y; i < 32; i += 8){
    int r = r0 + i, k = k0 + x;
    tl[i][x] = (r < R && k < K) ? in[(size_t)r*ldin + k] : 0.f;
  }
  __syncthreads();
  for (int i = y; i < 32; i += 8){
    int k = k0 + i, r = r0 + x;
    if (k < K8 && r < R) out[((size_t)(k >> 3)*R + r)*8 + (k & 7)] = f2bf(tl[x][i]);
  }
}

// fp32 -> bf16 bulk convert (4 elems/thread)
__global__ __launch_bounds__(256) void cvtbf_k(const float* __restrict__ src,
    unsigned short* __restrict__ dst, int n4){
  int i = blockIdx.x*256 + threadIdx.x;
  if (i >= n4) return;
  float4 v = ((const float4*)src)[i];
  ushort4 o; o.x = f2bf(v.x); o.y = f2bf(v.y); o.z = f2bf(v.z); o.w = f2bf(v.w);
  ((ushort4*)dst)[i] = o;
}

// K-transpose for encoder attention
__global__ void kt_k(const float* __restrict__ QKV, float* __restrict__ KT){
  __shared__ float t[32][33];
  int z = blockIdx.z; int b = z >> 2, h = z & 3;
  const float* in = QKV + (size_t)b*L_ENC*1152 + 384 + h*HDIM;
  float* out = KT + (size_t)z*HDIM*L_ENC;
  int c0 = blockIdx.x*32, r0 = blockIdx.y*32;
  int x = threadIdx.x, y = threadIdx.y;
  for (int i = y; i < 32; i += 8){
    int r = r0 + i, c = c0 + x;
    t[i][x] = (r < L_ENC && c < HDIM) ? in[(size_t)r*1152 + c] : 0.f;
  }
  __syncthreads();
  for (int i = y; i < 32; i += 8){
    int c = c0 + i, r = r0 + x;
    if (c < HDIM && r < L_ENC) out[(size_t)c*L_ENC + r] = t[x][i];
  }
}

// ---------------------------------------------------------------------------
// Generic fp32 GEMM: C[M,N] = act(A[M,K] @ W[N,K]^T + bias[N] (+ Res[M,N]))
template<int RELU, int HASRES>
__global__ __launch_bounds__(256) void gemm_k(
    const float* __restrict__ A, int lda, const float* __restrict__ W, int ldw,
    const float* __restrict__ bias, const float* __restrict__ Res,
    float* __restrict__ C, int ldc, int M, int N, int K)
{
  __shared__ __align__(16) float As[16][132];
  __shared__ __align__(16) float Ws[16][68];
  int tid = threadIdx.x;
  int row0 = blockIdx.y*128, col0 = blockIdx.x*64;
  int tx = tid & 15, ty = tid >> 4;
  int lr = tid >> 2, lk = (tid & 3)*4;
  float acc[8][4] = {};
  for (int k0 = 0; k0 < K; k0 += 16){
    float4 a0 = make_float4(0,0,0,0), a1 = make_float4(0,0,0,0), w0 = make_float4(0,0,0,0);
    int r0i = row0 + lr, r1i = row0 + 64 + lr, wri = col0 + lr;
    if (r0i < M) a0 = *(const float4*)(A + (size_t)r0i*lda + k0 + lk);
    if (r1i < M) a1 = *(const float4*)(A + (size_t)r1i*lda + k0 + lk);
    if (wri < N) w0 = *(const float4*)(W + (size_t)wri*ldw + k0 + lk);
    As[lk+0][lr] = a0.x; As[lk+1][lr] = a0.y; As[lk+2][lr] = a0.z; As[lk+3][lr] = a0.w;
    As[lk+0][64+lr] = a1.x; As[lk+1][64+lr] = a1.y; As[lk+2][64+lr] = a1.z; As[lk+3][64+lr] = a1.w;
    Ws[lk+0][lr] = w0.x; Ws[lk+1][lr] = w0.y; Ws[lk+2][lr] = w0.z; Ws[lk+3][lr] = w0.w;
    __syncthreads();
    #pragma unroll
    for (int k = 0; k < 16; k++){
      float4 b4 = *(const float4*)&Ws[k][tx*4];
      float4 a4 = *(const float4*)&As[k][ty*8];
      float4 a5 = *(const float4*)&As[k][ty*8+4];
      acc[0][0] += a4.x*b4.x; acc[0][1] += a4.x*b4.y; acc[0][2] += a4.x*b4.z; acc[0][3] += a4.x*b4.w;
      acc[1][0] += a4.y*b4.x; acc[1][1] += a4.y*b4.y; acc[1][2] += a4.y*b4.z; acc[1][3] += a4.y*b4.w;
      acc[2][0] += a4.z*b4.x; acc[2][1] += a4.z*b4.y; acc[2][2] += a4.z*b4.z; acc[2][3] += a4.z*b4.w;
      acc[3][0] += a4.w*b4.x; acc[3][1] += a4.w*b4.y; acc[3][2] += a4.w*b4.z; acc[3][3] += a4.w*b4.w;
      acc[4][0] += a5.x*b4.x; acc[4][1] += a5.x*b4.y; acc[4][2] += a5.x*b4.z; acc[4][3] += a5.x*b4.w;
      acc[5][0] += a5.y*b4.x; acc[5][1] += a5.y*b4.y; acc[5][2] += a5.y*b4.z; acc[5][3] += a5.y*b4.w;
      acc[6][0] += a5.z*b4.x; acc[6][1] += a5.z*b4.y; acc[6][2] += a5.z*b4.z; acc[6][3] += a5.z*b4.w;
      acc[7][0] += a5.w*b4.x; acc[7][1] += a5.w*b4.y; acc[7][2] += a5.w*b4.z; acc[7][3] += a5.w*b4.w;
    }
    __syncthreads();
  }
  #pragma unroll
  for (int ii = 0; ii < 8; ii++){
    int m = row0 + ty*8 + ii;
    if (m >= M) continue;
    #pragma unroll
    for (int jj = 0; jj < 4; jj++){
      int n = col0 + tx*4 + jj;
      if (n >= N) continue;
      float v = acc[ii][jj] + bias[n];
      if (HASRES) v += Res[(size_t)m*ldc + n];
      if (RELU) v = fmaxf(v, 0.f);
      C[(size_t)m*ldc + n] = v;
    }
  }
}

// ---------------------------------------------------------------------------
// im2col for conv1 (k=3, pad=1, stride=1)
__global__ void im2col1(const float* __restrict__ in, float* __restrict__ P){
  int t = blockIdx.x, b = blockIdx.y, i = threadIdx.x;
  if (i >= 240) return;
  int ic = i/3, kt = i - ic*3;
  int p = t + kt - 1;
  P[((size_t)(b*T_AUD + t))*240 + i] = (p >= 0 && p < T_AUD) ? in[((size_t)(b*80 + ic))*T_AUD + p] : 0.f;
}

// im2col for conv2 (k=3, pad=1, stride=2)
__global__ __launch_bounds__(384) void im2col2(const float* __restrict__ X1T, float* __restrict__ P){
  int t = blockIdx.x, b = blockIdx.y, ic = threadIdx.x;
  size_t ob = ((size_t)(b*L_ENC + t))*1152 + (size_t)ic*3;
  #pragma unroll
  for (int kt = 0; kt < 3; kt++){
    int p = 2*t + kt - 1;
    P[ob + kt] = (p >= 0 && p < T_AUD) ? X1T[((size_t)(b*T_AUD + p))*DD + ic] : 0.f;
  }
}

// Vectorized dup (rocclr D2D blit is ~serial)
__global__ __launch_bounds__(256) void dup_k(const float* __restrict__ src,
    float* __restrict__ a, float* __restrict__ b){
  size_t i = (size_t)blockIdx.x*256 + threadIdx.x;
  float4 v = ((const float4*)src)[i];
  ((float4*)a)[i] = v;
  ((float4*)b)[i] = v;
}

// ---------------------------------------------------------------------------
// LayerNorm in-place over rows of 384
__global__ __launch_bounds__(128) void ln_k(float* __restrict__ X, const float* __restrict__ g,
                                            const float* __restrict__ bt){
  int r = blockIdx.x, tid = threadIdx.x;
  float* p = X + (size_t)r*DD;
  float v0 = p[tid], v1 = p[tid+128], v2 = p[tid+256];
  __shared__ float red[128];
  red[tid] = v0+v1+v2; __syncthreads();
  for (int k = 64; k > 0; k >>= 1){ if (tid < k) red[tid] += red[tid+k]; __syncthreads(); }
  float m = red[0] * (1.f/384.f);
  __syncthreads();
  float d0 = v0-m, d1 = v1-m, d2 = v2-m;
  red[tid] = d0*d0 + d1*d1 + d2*d2; __syncthreads();
  for (int k = 64; k > 0; k >>= 1){ if (tid < k) red[tid] += red[tid+k]; __syncthreads(); }
  float rs = rsqrtf(red[0]*(1.f/384.f) + 1e-5f);
  p[tid]     = d0*rs*g[tid]     + bt[tid];
  p[tid+128] = d1*rs*g[tid+128] + bt[tid+128];
  p[tid+256] = d2*rs*g[tid+256] + bt[tid+256];
}

// ---------------------------------------------------------------------------
// Encoder attention, fused scores+softmax+AV. 16 rows per block (wave per row).
__global__ __launch_bounds__(1024) void attn_enc(const float* __restrict__ QKV,
    const float* __restrict__ KT, float* __restrict__ ctx){
  int b = blockIdx.z, h = blockIdx.y, i0 = blockIdx.x*16;
  int tid = threadIdx.x, lane = tid & 63, wv = tid >> 6;
  __shared__ float q_s[16][96];
  __shared__ float p_s[16][752];
  __shared__ float den_s[16];
  for (int idx = tid; idx < 16*96; idx += 1024){
    int r2 = idx/96, c = idx - r2*96; int i = i0 + r2;
    q_s[r2][c] = (i < L_ENC) ? QKV[((size_t)(b*L_ENC + i))*1152 + h*HDIM + c]*0.10206207f : 0.f;
  }
  __syncthreads();
  int i = i0 + wv;
  const float* ktb = KT + ((size_t)(b*4 + h))*HDIM*L_ENC;
  if (i < L_ENC){
    float sr[12] = {0,0,0,0,0,0,0,0,0,0,0,0};
    for (int c = 0; c < 96; c++){
      float qc = q_s[wv][c];
      const float* kr = ktb + c*L_ENC + lane;
      #pragma unroll
      for (int jt = 0; jt < 12; jt++) sr[jt] += qc*kr[jt*64];
    }
    float mx = -1e30f;
    #pragma unroll
    for (int jt = 0; jt < 12; jt++){ if (lane + jt*64 < L_ENC) mx = fmaxf(mx, sr[jt]); }
    #pragma unroll
    for (int o = 32; o > 0; o >>= 1) mx = fmaxf(mx, __shfl_xor(mx, o));
    float den = 0.f;
    #pragma unroll
    for (int jt = 0; jt < 12; jt++){
      int j = lane + jt*64;
      if (j < L_ENC){ float e = __expf(sr[jt]-mx); p_s[wv][j] = e; den += e; }
    }
    #pragma unroll
    for (int o = 32; o > 0; o >>= 1) den += __shfl_xor(den, o);
    if (lane == 0) den_s[wv] = den;
  }
  __syncthreads();
  if (i < L_ENC){
    float idn = 1.f/den_s[wv];
    const float* vb = QKV + (size_t)b*L_ENC*1152 + 768 + h*HDIM;
    float a0 = 0.f, a1 = 0.f;
    for (int j = 0; j < L_ENC; j++){
      float pj = p_s[wv][j];
      const float* vr = vb + (size_t)j*1152;
      a0 += pj*vr[lane];
      if (lane < 32) a1 += pj*vr[lane + 64];
    }
    size_t ob = ((size_t)(b*L_ENC + i))*DD + h*HDIM;
    ctx[ob + lane] = a0*idn;
    if (lane < 32) ctx[ob + lane + 64] = a1*idn;
  }
}

// ---------------------------------------------------------------------------
// Decode precompute helpers
__global__ __launch_bounds__(384) void embed_k(const float* __restrict__ emb,
    const int* __restrict__ tgtA, float* __restrict__ E){
  int row = blockIdx.x; int t = row >> 3, b = row & 7;
  int tok = 0;
  if (t > 0){ int v = tgtA[b*T_TXT + t - 1]; tok = (v == -100) ? 0 : v; }
  E[(size_t)row*DD + threadIdx.x] = emb[(size_t)tok*DD + threadIdx.x];
}

__global__ __launch_bounds__(256) void vla_k(const float* __restrict__ EA,
    const float* __restrict__ lav, const float* __restrict__ lain, float* __restrict__ VLA){
  int row = blockIdx.x*4 + (threadIdx.x >> 6);
  int lane = threadIdx.x & 63;
  if (row >= BB*L_ENC) return;
  const float* p = EA + (size_t)row*DD;
  float s = 0.f;
  for (int d = lane; d < DD; d += 64) s += p[d]*lav[d];
  #pragma unroll
  for (int o = 32; o > 0; o >>= 1) s += __shfl_xor(s, o);
  if (lane == 0) VLA[row] = s + lain[2];
}

__global__ void invn_k(const float* __restrict__ inv, float* __restrict__ INVN){
  int row = blockIdx.x; int lane = threadIdx.x;
  float s = 0.f;
  for (int d = lane; d < DD; d += 64){ float v = inv[(size_t)row*DD + d]; s += v*v; }
  #pragma unroll
  for (int o = 32; o > 0; o >>= 1) s += __shfl_xor(s, o);
  if (lane == 0) INVN[row] = sqrtf(s);
}

// ---------------------------------------------------------------------------
struct DecParams {
  float* ws; float* out;
  const float* ABHH; const float* DBHH;
  const float* SPK;  const float* AOB;
  const float* LAQ; const float* LAK; const float* LAIB; const float* LAOW; const float* LAOB;
  const float* H2AB; const float* D2AB;
  const int* TGTA; const int* TGTD;
};

// Grid barrier: distributed arrival slots + distributed broadcast flags.
static __device__ __forceinline__ void gbar(unsigned* s, unsigned epoch){
  __syncthreads();
  int tid = threadIdx.x;
  if (blockIdx.x == 0){
    if (tid > 0 && tid < NB){
      while (__hip_atomic_load(&s[tid*4], __ATOMIC_RELAXED, __HIP_MEMORY_SCOPE_AGENT) < epoch)
        __builtin_amdgcn_s_sleep(4);
    }
    __syncthreads();
    if (tid < NB)
      __hip_atomic_store(&s[(512 + tid)*4], epoch, __ATOMIC_RELAXED, __HIP_MEMORY_SCOPE_AGENT);
  } else {
    if (tid == 0){
      __hip_atomic_store(&s[blockIdx.x*4], epoch, __ATOMIC_RELAXED, __HIP_MEMORY_SCOPE_AGENT);
      while (__hip_atomic_load(&s[(512 + blockIdx.x)*4], __ATOMIC_RELAXED, __HIP_MEMORY_SCOPE_AGENT) < epoch)
        __builtin_amdgcn_s_sleep(4);
    }
    __syncthreads();
  }
}

// NOTE: macro params must NOT be named after vector members (w/x/y/z).
#define FMA8(acc, s_, base) { const float4 b0_ = *(const float4*)&(base)[0]; const float4 b1_ = *(const float4*)&(base)[4]; \
  acc[0]+=b0_.x*(s_); acc[1]+=b0_.y*(s_); acc[2]+=b0_.z*(s_); acc[3]+=b0_.w*(s_); \
  acc[4]+=b1_.x*(s_); acc[5]+=b1_.y*(s_); acc[6]+=b1_.z*(s_); acc[7]+=b1_.w*(s_); }

// 8 bf16 weights (uint4) against 8 consecutive k-slots of LDS ac/hh
#define GFMA8(acc, wv_, a_) { \
  FMA8(acc, bf2f(wv_.x & 0xffffu), (a_)+0);  FMA8(acc, bf2f(wv_.x >> 16), (a_)+8); \
  FMA8(acc, bf2f(wv_.y & 0xffffu), (a_)+16); FMA8(acc, bf2f(wv_.y >> 16), (a_)+24); \
  FMA8(acc, bf2f(wv_.z & 0xffffu), (a_)+32); FMA8(acc, bf2f(wv_.z >> 16), (a_)+40); \
  FMA8(acc, bf2f(wv_.w & 0xffffu), (a_)+48); FMA8(acc, bf2f(wv_.w >> 16), (a_)+56); }

// GRU gate pre-activations: one 16-row task per block, 512 thr = 32 k-partitions.
// Weights bf16 packed [K/8][NR][8] -> uint4 loads. KOH = h-octs (asr 94, diar 48).
template<int NR, int KH, int KOH>
__device__ void gates_fn(int task, const unsigned short* __restrict__ WIT,
                         const unsigned short* __restrict__ WHT,
                         const float* __restrict__ ctxv, const float* __restrict__ hv,
                         const float* __restrict__ GE, const float* __restrict__ bhh,
                         float* __restrict__ GI, float* __restrict__ GH, int t, float* SM)
{
  float* ac  = SM;                  // [48 octs]*64 = 3072
  float* hh  = SM + 3072;           // KOH*64
  float* pgi = SM + 3072 + KOH*64;  // [32][16][8] = 4096
  float* pgh = pgi + 4096;          // 4096
  int tid = threadIdx.x;
  for (int idx = tid; idx < 3072; idx += TB){ int b = idx/384, k = idx - b*384; ac[k*8+b] = cld(&ctxv[idx]); }
  for (int idx = tid; idx < KH*8;  idx += TB){ int b = idx/KH,  k = idx - b*KH;  hh[k*8+b] = cld(&hv[idx]); }
  for (int idx = KH*8 + tid; idx < KOH*64; idx += TB) hh[idx] = 0.f;
  __syncthreads();
  int rl = tid & 15, kp = tid >> 4;   // 32 k-partitions x 16 rows
  int r = task*16 + rl;
  float gi[8] = {}, gh[8] = {};
  if (r < NR){
    const uint4* W4 = (const uint4*)WIT;
    int q0 = (kp*48) >> 5, q1 = ((kp+1)*48) >> 5;   // 48 octs over 32 partitions
    for (int q = q0; q < q1; q++){
      uint4 wq = W4[(size_t)q*NR + r];
      const float* a = &ac[q*64];
      GFMA8(gi, wq, a);
    }
    const uint4* WH4 = (const uint4*)WHT;
    int h0 = (kp*KOH) >> 5, h1 = ((kp+1)*KOH) >> 5;
    for (int q = h0; q < h1; q++){
      uint4 wq = WH4[(size_t)q*NR + r];
      const float* a = &hh[q*64];
      GFMA8(gh, wq, a);
    }
  }
  #pragma unroll
  for (int b = 0; b < 8; b++){ pgi[(kp*16+rl)*8 + b] = gi[b]; pgh[(kp*16+rl)*8 + b] = gh[b]; }
  __syncthreads();
  if (tid < 128){
    int rl2 = tid & 15, bb = tid >> 4;
    int rr = task*16 + rl2;
    if (rr < NR){
      float s1 = 0.f, s2 = 0.f;
      #pragma unroll
      for (int kq = 0; kq < 32; kq++){ s1 += pgi[(kq*16+rl2)*8+bb]; s2 += pgh[(kq*16+rl2)*8+bb]; }
      cst(&GI[(size_t)bb*NR + rr], s1 + GE[((size_t)t*8 + bb)*NR + rr]);
      cst(&GH[(size_t)bb*NR + rr], s2 + bhh[rr]);
    }
  }
  __syncthreads();
}

// Phase A worker: asr GRU combine + rank-1 attention only (ctx moved to A2).
// 464 blocks: b = bid&7, chunk = bid>>3 (58 chunks of 13 rows).
__device__ void phase_hattn(int bid, int t, float* ws, const DecParams& P, float* SM)
{
  float* kk = SM;            // 768
  float* vv = SM + 768;      // 768
  int tid = threadIdx.x;
  int b = bid & 7, chunk = bid >> 3;
  int i0 = chunk*13; int n = L_ENC - i0; if (n > 13) n = 13;
  const float* acur = ws + ((t & 1) ? oATT1 : oATT0);
  float*       anxt = ws + ((t & 1) ? oATT0 : oATT1);
  const float* GIAp = ws + oGIA; const float* GHAp = ws + oGHA;
  float* HASRp = ws + oHASR;
  const float* VLAp = ws + oVLA;
  float kw = P.LAK[0], kb = P.LAIB[1];
  for (int j = tid; j < L_ENC; j += TB){
    kk[j] = cld(&acur[b*L_ENC + j])*kw + kb;
    vv[j] = VLAp[b*L_ENC + j];
  }
  __syncthreads();
  int wv = tid >> 6, lane = tid & 63;
  float laq = P.LAQ[0], li0 = P.LAIB[0], low = P.LAOW[0], lob = P.LAOB[0];
  for (int il = wv; il < n; il += 8){
    int i = i0 + il;
    int base = b*2250 + i;
    float rr = sigmf(cld(&GIAp[base]) + cld(&GHAp[base]));
    float zz = sigmf(cld(&GIAp[base+750]) + cld(&GHAp[base+750]));
    float nn = tanhf(cld(&GIAp[base+1500]) + rr*cld(&GHAp[base+1500]));
    float h = (1.f - zz)*nn + zz*cld(&HASRp[b*L_ENC + i]);
    float q = h*laq + li0;
    float sr[12]; float mx = -1e30f;
    #pragma unroll
    for (int jt = 0; jt < 12; jt++){
      int j = lane + jt*64;
      float s = (j < L_ENC) ? q*kk[j] : -1e30f;
      sr[jt] = s; mx = fmaxf(mx, s);
    }
    #pragma unroll
    for (int o = 32; o > 0; o >>= 1) mx = fmaxf(mx, __shfl_xor(mx, o));
    float se = 0.f, sv = 0.f;
    #pragma unroll
    for (int jt = 0; jt < 12; jt++){
      int j = lane + jt*64;
      if (j < L_ENC){ float e = __expf(sr[jt] - mx); se += e; sv += e*vv[j]; }
    }
    #pragma unroll
    for (int o = 32; o > 0; o >>= 1){ se += __shfl_xor(se, o); sv += __shfl_xor(sv, o); }
    if (lane == 0){
      cst(&HASRp[b*L_ENC + i], h);
      cst(&anxt[b*L_ENC + i], (sv/se)*low + lob);
    }
  }
  __syncthreads();
}

// Phase A2: context GEMV, single-writer, ZERO atomics. 96 blocks = 8 b x 12
// d-chunks(32). 512 thr = 16 l-strips x 32 d. EA/ED/H2AT bf16 are L2-resident.
__device__ void phase_ctx(int bid, int t, float* ws,
                          const unsigned short* __restrict__ EAh,
                          const unsigned short* __restrict__ EDh,
                          const unsigned short* __restrict__ H2h,
                          const DecParams& P, float* SM)
{
  float* wl   = SM;           // 768
  float* hl   = SM + 768;     // 768
  float* reda = SM + 1536;    // 512
  float* reds = SM + 2048;    // 512
  float* redh = SM + 2560;    // 512
  int tid = threadIdx.x;
  int b = bid & 7, dc = bid >> 3;
  int d0 = dc*32;
  const float* anxt = ws + ((t & 1) ? oATT0 : oATT1);  // ATT(t) written by hattn(t)
  const float* HASRp = ws + oHASR;
  for (int j = tid; j < L_ENC; j += TB){
    wl[j] = cld(&anxt[b*L_ENC + j]);
    hl[j] = cld(&HASRp[b*L_ENC + j]);
  }
  __syncthreads();
  int ls = tid >> 5, dx = tid & 31;
  int d = d0 + dx;
  const unsigned short* EAb = EAh + (size_t)b*L_ENC*DD + d;
  const unsigned short* EDb = EDh + (size_t)b*L_ENC*DD + d;
  const unsigned short* H2b = H2h + d;
  float a = 0.f, s = 0.f, hp = 0.f;
  for (int l = ls; l < L_ENC; l += 16){
    size_t lo = (size_t)l*DD;
    float wj = wl[l], hj = hl[l];
    a  += bf2f(EAb[lo])*wj;
    s  += bf2f(EDb[lo])*wj;
    hp += bf2f(H2b[lo])*hj;
  }
  reda[tid] = a; reds[tid] = s; redh[tid] = hp;
  __syncthreads();
  if (tid < 32){
    float ra = 0.f, rs = 0.f, rh = 0.f;
    #pragma unroll
    for (int q = 0; q < 16; q++){
      ra += reda[q*32+tid]; rs += reds[q*32+tid]; rh += redh[q*32+tid];
    }
    int dd = d0 + tid;
    cst(&ws[oACTX + b*DD + dd], ra);
    cst(&ws[oSCTX + b*DD + dd], rs);
    cst(&ws[oPREP + b*DD + dd], P.H2AB[dd] + P.D2AB[dd] + ra + rh);
  }
  __syncthreads();
}

// Phase: diar GRU combine + speaker softmax + logits + loss. One block per b.
__device__ void phase_final(int b, int t, float* ws, const float* prep,
                            const DecParams& P, float* SM)
{
  float* hd_s = SM;            // 384
  float* pre_s = SM + 384;     // 384
  float* red = SM + 768;       // 512
  float* beta_s = SM + 1280;   // 8
  float* sc_s = SM + 1288;     // 8
  float* part2 = SM + 1296;    // 8*64
  int tid = threadIdx.x;
  bool act = tid < DD;
  const float* GIDp = ws + oGID; const float* GHDp = ws + oGHD;
  float* HDp = ws + oHD;
  float h = 0.f;
  if (act){
    int base = b*1152 + tid;
    float rr = sigmf(cld(&GIDp[base]) + cld(&GHDp[base]));
    float zz = sigmf(cld(&GIDp[base+384]) + cld(&GHDp[base+384]));
    float nn = tanhf(cld(&GIDp[base+768]) + rr*cld(&GHDp[base+768]));
    h = (1.f - zz)*nn + zz*cld(&HDp[b*DD + tid]);
    hd_s[tid] = h; cst(&HDp[b*DD + tid], h);
  }
  red[tid] = act ? h*h : 0.f;
  __syncthreads();
  for (int s = 256; s > 0; s >>= 1){ if (tid < s) red[tid] += red[tid+s]; __syncthreads(); }
  float hn = sqrtf(red[0]);
  int sg = tid >> 6, lane = tid & 63;
  float ps = 0.f;
  for (int j = lane; j < DD; j += 64) ps += P.SPK[((size_t)(b*8 + sg))*DD + j]*hd_s[j];
  #pragma unroll
  for (int o = 32; o > 0; o >>= 1) ps += __shfl_xor(ps, o);
  if (lane == 0) sc_s[sg] = ps / (hn * ws[oINVN + b*8 + sg]);
  __syncthreads();
  if (tid == 0){
    float mx = -1e30f;
    for (int s2 = 0; s2 < 8; s2++) mx = fmaxf(mx, sc_s[s2]);
    float sm = 0.f;
    for (int s2 = 0; s2 < 8; s2++){ float e = __expf(sc_s[s2] - mx); beta_s[s2] = e; sm += e; }
    float isv = 1.f/sm;
    for (int s2 = 0; s2 < 8; s2++) beta_s[s2] *= isv;
    int td = P.TGTD[b*T_TXT + t];
    if (td != -100){ atomicAdd(&ws[oLACC+2], beta_s[td]); atomicAdd(&ws[oLACC+3], 1.f); }
  }
  __syncthreads();
  if (tid < 8) P.out[122880 + ((size_t)(b*T_TXT + t))*8 + tid] = beta_s[tid];
  if (act){
    float p = cld(&prep[b*DD + tid]);
    const float* Mb = ws + oDIB + (size_t)(b*8)*DD + tid;
    #pragma unroll
    for (int s2 = 0; s2 < 8; s2++) p += beta_s[s2]*Mb[(size_t)s2*DD];
    pre_s[tid] = p;
  }
  __syncthreads();
  {
    int vg = tid >> 6, v = tid & 63;
    float pl = 0.f;
    if (v < VOCAB){
      const float* AOTp = ws + oAOT;
      int d0 = vg*48;
      for (int d2 = d0; d2 < d0+48; d2++) pl += pre_s[d2]*AOTp[d2*VOCAB + v];
    }
    part2[vg*64 + v] = pl;
  }
  __syncthreads();
  if (tid < VOCAB){
    float lg = P.AOB[tid];
    #pragma unroll
    for (int g = 0; g < 8; g++) lg += part2[g*64 + tid];
    P.out[((size_t)(b*T_TXT + t))*VOCAB + tid] = lg;
    int ta = P.TGTA[b*T_TXT + t];
    if (ta == tid) atomicAdd(&ws[oLACC+0], lg);
    if (tid == 0 && ta != -100) atomicAdd(&ws[oLACC+1], 1.f);
  }
  __syncthreads();
}

// Persistent decode loop (480 blocks, 2/CU), 3 barriers per step:
// A:  hattn(t)[0..463] || final(t-1)[464..471]
// A2: ctx(t)[0..95]   (single-writer, no atomics)
// B:  gates_D(t)[0..71] || gates_A(t+1)[72..212]
__global__ __launch_bounds__(TB, 4) void dec_loop(DecParams P)
{
  __shared__ __align__(16) float SM[17280];   // 69.1 KB (2 blocks/CU = 138 KB)
  int bid = blockIdx.x;
  float* ws = P.ws;
  unsigned* slots = (unsigned*)(ws + oBAR);
  unsigned ep = 0;
  const unsigned short* WIA = (const unsigned short*)(ws + oWIHAT_A);
  const unsigned short* WHA = (const unsigned short*)(ws + oWHHT_A);
  const unsigned short* WID = (const unsigned short*)(ws + oWIHAT_D);
  const unsigned short* WHD = (const unsigned short*)(ws + oWHHT_D);
  const unsigned short* EAh = (const unsigned short*)(ws + oEAh);
  const unsigned short* EDh = (const unsigned short*)(ws + oEDh);
  const unsigned short* H2h = (const unsigned short*)(ws + oH2ATh);

  // prologue: asr gates(0) (ACTX=HASR=0 from memset)
  if (bid < 141)
    gates_fn<2250,750,94>(bid, WIA, WHA, ws+oACTX, ws+oHASR,
                          ws+oGEA, P.ABHH, ws+oGIA, ws+oGHA, 0, SM);
  gbar(slots, ++ep);

  for (int t = 0; t <= T_TXT; t++){
    // ---- Phase A ----
    if (t < T_TXT && bid < 464) phase_hattn(bid, t, ws, P, SM);
    else if (bid >= 464 && bid < 472 && t >= 1)
      phase_final(bid - 464, t - 1, ws, ws + oPREP, P, SM);
    gbar(slots, ++ep);
    if (t == T_TXT) break;

    // ---- Phase A2 ----
    if (bid < 96) phase_ctx(bid, t, ws, EAh, EDh, H2h, P, SM);
    gbar(slots, ++ep);

    // ---- Phase B ----
    if (bid < 72)
      gates_fn<1152,384,48>(bid, WID, WHD, ws+oSCTX, ws+oHD,
                            ws+oGED, P.DBHH, ws+oGID, ws+oGHD, t, SM);
    else if (bid < 213 && t + 1 < T_TXT)
      gates_fn<2250,750,94>(bid-72, WIA, WHA, ws+oACTX, ws+oHASR,
                            ws+oGEA, P.ABHH, ws+oGIA, ws+oGHA, t+1, SM);
    gbar(slots, ++ep);
  }
}

__global__ void loss_final_k(const float* __restrict__ lacc, float* __restrict__ out){
  if (threadIdx.x == 0 && blockIdx.x == 0){
    float la = lacc[0]/fmaxf(lacc[1], 1.f);
    float ld = lacc[2]/fmaxf(lacc[3], 1.f);
    out[139264] = -(la + ld);
  }
}

// ---------------------------------------------------------------------------
extern "C" void kernel_launch(void* const* d_in, const int* in_sizes, int n_in,
                              void* d_out, int out_size, void* d_ws, size_t ws_size,
                              hipStream_t stream)
{
  (void)in_sizes; (void)n_in; (void)out_size; (void)ws_size;
  float* ws  = (float*)d_ws;
  float* out = (float*)d_out;

  const float* IN0   = (const float*)d_in[0];
  const float* SPK   = (const float*)d_in[1];
  const float* C1W   = (const float*)d_in[2];
  const float* C1B   = (const float*)d_in[3];
  const float* C2W   = (const float*)d_in[4];
  const float* C2B   = (const float*)d_in[5];
  const float* LAQ   = (const float*)d_in[30];
  const float* LAK   = (const float*)d_in[31];
  const float* LAV   = (const float*)d_in[32];
  const float* LAIB  = (const float*)d_in[33];
  const float* LAOW  = (const float*)d_in[34];
  const float* LAOB  = (const float*)d_in[35];
  const float* EMB   = (const float*)d_in[36];
  const float* AWIH  = (const float*)d_in[37];
  const float* AWHH  = (const float*)d_in[38];
  const float* ABIH  = (const float*)d_in[39];
  const float* ABHH  = (const float*)d_in[40];
  const float* DWIH  = (const float*)d_in[41];
  const float* DWHH  = (const float*)d_in[42];
  const float* DBIH  = (const float*)d_in[43];
  const float* DBHH  = (const float*)d_in[44];
  const float* AOW   = (const float*)d_in[45];
  const float* AOB   = (const float*)d_in[46];
  const float* D2AW  = (const float*)d_in[47];
  const float* D2AB  = (const float*)d_in[48];
  const float* H2AW  = (const float*)d_in[49];
  const float* H2AB  = (const float*)d_in[50];
  const int*   TGTA  = (const int*)d_in[51];
  const int*   TGTD  = (const int*)d_in[52];

  // encoder scratch overlay (float offsets, relative to ws)
  const size_t S_QKV = O_SCR;
  const size_t S_KT  = O_SCR + 6912000;
  const size_t S_CTX = O_SCR + 9216000;
  const size_t S_Y   = O_SCR + 11520000;
  const size_t S_H   = O_SCR + 13824000;
  const size_t X1T   = S_KT;
  const size_t Pc1   = S_H;
  const size_t Pc2   = S_QKV;

  // 1) zero decode state + loss accumulators + barrier slots/flags + zero-bias
  hipMemsetAsync((void*)(ws + O_ST), 0, 105000*sizeof(float), stream);

  // 2) convs via im2col + GEMM
  im2col1<<<dim3(1500,8), 256, 0, stream>>>(IN0, ws + Pc1);
  gemm_k<1,0><<<dim3(6,94), 256, 0, stream>>>(ws+Pc1, 240, C1W, 240, C1B, nullptr, ws+X1T, 384, 12000, 384, 240);
  im2col2<<<dim3(750,8), 384, 0, stream>>>(ws+X1T, ws+Pc2);
  gemm_k<1,0><<<dim3(6,47), 256, 0, stream>>>(ws+Pc2, 1152, C2W, 1152, C2B, nullptr, ws+O_X, 384, 6000, 384, 1152);

  dup_k<<<2250, 256, 0, stream>>>(ws+O_X, ws+O_EA, ws+O_ED);

  // 3) encoder stacks
  auto enc_layer = [&](float* Xb, const float* qw, const float* qb, const float* ow,
                       const float* ob, const float* f1w, const float* f1b,
                       const float* f2w, const float* f2b,
                       const float* g1, const float* b1, const float* g2, const float* b2){
    gemm_k<0,0><<<dim3(18,47), 256, 0, stream>>>(Xb, 384, qw, 384, qb, nullptr, ws+S_QKV, 1152, 6000, 1152, 384);
    kt_k<<<dim3(3,24,32), dim3(32,8), 0, stream>>>(ws+S_QKV, ws+S_KT);
    attn_enc<<<dim3(47,4,8), 1024, 0, stream>>>(ws+S_QKV, ws+S_KT, ws+S_CTX);
    gemm_k<0,1><<<dim3(6,47), 256, 0, stream>>>(ws+S_CTX, 384, ow, 384, ob, Xb, ws+S_Y, 384, 6000, 384, 384);
    ln_k<<<6000, 128, 0, stream>>>(ws+S_Y, g1, b1);
    gemm_k<1,0><<<dim3(16,47), 256, 0, stream>>>(ws+S_Y, 384, f1w, 384, f1b, nullptr, ws+S_H, 1024, 6000, 1024, 384);
    gemm_k<0,1><<<dim3(6,47), 256, 0, stream>>>(ws+S_H, 1024, f2w, 1024, f2b, ws+S_Y, Xb, 384, 6000, 384, 1024);
    ln_k<<<6000, 128, 0, stream>>>(Xb, g2, b2);
  };
  for (int st = 0; st < 2; st++){
    int base = (st == 0) ? 6 : 18;
    float* Xb = ws + ((st == 0) ? O_EA : O_ED);
    const float* qkvw = (const float*)d_in[base+0];
    const float* qkvb = (const float*)d_in[base+1];
    const float* aow  = (const float*)d_in[base+2];
    const float* aob2 = (const float*)d_in[base+3];
    const float* f1w  = (const float*)d_in[base+4];
    const float* f1b  = (const float*)d_in[base+5];
    const float* f2w  = (const float*)d_in[base+6];
    const float* f2b  = (const float*)d_in[base+7];
    const float* g1   = (const float*)d_in[base+8];
    const float* b1   = (const float*)d_in[base+9];
    const float* g2   = (const float*)d_in[base+10];
    const float* b2   = (const float*)d_in[base+11];
    for (int l = 0; l < 2; l++){
      enc_layer(Xb, qkvw + (size_t)l*1152*384, qkvb + (size_t)l*1152,
                aow + (size_t)l*384*384, aob2 + (size_t)l*384,
                f1w + (size_t)l*1024*384, f1b + (size_t)l*1024,
                f2w + (size_t)l*384*1024, f2b + (size_t)l*384,
                g1 + (size_t)l*384, b1 + (size_t)l*384, g2 + (size_t)l*384, b2 + (size_t)l*384);
    }
  }

  // 4) decode precompute (overlays encoder scratch; after encoder completes)
  packTbf_k<<<dim3(12,71), dim3(32,8), 0, stream>>>(AWIH, 768, 2250, 384, (unsigned short*)(ws+oWIHAT_A));
  packTbf_k<<<dim3(24,71), dim3(32,8), 0, stream>>>(AWHH, 750, 2250, 750, (unsigned short*)(ws+oWHHT_A));
  packTbf_k<<<dim3(12,36), dim3(32,8), 0, stream>>>(DWIH, 768, 1152, 384, (unsigned short*)(ws+oWIHAT_D));
  packTbf_k<<<dim3(12,36), dim3(32,8), 0, stream>>>(DWHH, 384, 1152, 384, (unsigned short*)(ws+oWHHT_D));
  transpose_k<<<dim3(24,12), dim3(32,8), 0, stream>>>(H2AW, 750, 384, 750, ws+oTMPH);
  cvtbf_k<<<282, 256, 0, stream>>>(ws+oTMPH, (unsigned short*)(ws+oH2ATh), 72000);
  transpose_k<<<dim3(12,2),  dim3(32,8), 0, stream>>>(AOW, 384, 60, 384, ws+oAOT);
  embed_k<<<2048, 384, 0, stream>>>(EMB, TGTA, ws+oEMBT);
  gemm_k<0,0><<<dim3(36,16), 256, 0, stream>>>(ws+oEMBT, 384, AWIH+384, 768, ABIH, nullptr, ws+oGEA, 2250, 2048, 2250, 384);
  gemm_k<0,0><<<dim3(18,16), 256, 0, stream>>>(ws+oEMBT, 384, DWIH+384, 768, DBIH, nullptr, ws+oGED, 1152, 2048, 1152, 384);
  // DIB = SPK(64x384) @ D2AW^T -> [64][384], zero bias
  gemm_k<0,0><<<dim3(6,1), 256, 0, stream>>>(SPK, 384, D2AW, 384, ws+oZ384, nullptr, ws+oDIB, 384, 64, 384, 384);
  vla_k<<<1500, 256, 0, stream>>>(ws+O_EA, LAV, LAIB, ws+oVLA);
  invn_k<<<64, 64, 0, stream>>>(SPK, ws+oINVN);
  cvtbf_k<<<2250, 256, 0, stream>>>(ws+O_EA, (unsigned short*)(ws+oEAh), 576000);
  cvtbf_k<<<2250, 256, 0, stream>>>(ws+O_ED, (unsigned short*)(ws+oEDh), 576000);

  // 5) persistent decode (480 blocks = 2/CU, 3 barriers/step, zero ctx atomics)
  DecParams DP;
  DP.ws = ws; DP.out = out;
  DP.ABHH = ABHH; DP.DBHH = DBHH; DP.SPK = SPK; DP.AOB = AOB;
  DP.LAQ = LAQ; DP.LAK = LAK; DP.LAIB = LAIB; DP.LAOW = LAOW; DP.LAOB = LAOB;
  DP.H2AB = H2AB; DP.D2AB = D2AB; DP.TGTA = TGTA; DP.TGTD = TGTD;
  dec_loop<<<dim3(NB), dim3(TB), 0, stream>>>(DP);

  loss_final_k<<<1, 64, 0, stream>>>(ws+oLACC, out);
}

// Round 12
// 20621.524 us; speedup vs baseline: 1.1191x; 1.1191x over previous
//
#include <hip/hip_runtime.h>
#include <math.h>

// ---------------------------------------------------------------------------
// Model constants
#define L_ENC 750
#define T_AUD 1500
#define DD    384
#define FF    1024
#define NHH   4
#define HDIM  96
#define VOCAB 60
#define T_TXT 256
#define BB    8
#define NB    480   // persistent decode grid: 2 blocks/CU, co-resident
#define TB    512   // decode block size (8 waves/block)

static __device__ __forceinline__ float sigmf(float x){ return 1.f/(1.f + __expf(-x)); }

// Coherent (coherence-point) accessors for mutable cross-block state.
static __device__ __forceinline__ float cld(const float* p){
  return __hip_atomic_load(p, __ATOMIC_RELAXED, __HIP_MEMORY_SCOPE_AGENT);
}
static __device__ __forceinline__ void cst(float* p, float v){
  __hip_atomic_store(p, v, __ATOMIC_RELAXED, __HIP_MEMORY_SCOPE_AGENT);
}

// ---------------------------------------------------------------------------
// workspace layout (float offsets)  [R7 layout, verbatim]
static constexpr size_t O_X  = 0;
static constexpr size_t O_EA = 2304000;
static constexpr size_t O_ED = 4608000;
static constexpr size_t O_ST = 6912000;
static constexpr size_t oHASR = O_ST + 0;        // 6000
static constexpr size_t oATT0 = O_ST + 6000;     // 6000
static constexpr size_t oATT1 = O_ST + 12000;    // 6000
static constexpr size_t oHD   = O_ST + 18000;    // 3072 (in-place GRU)
static constexpr size_t oACTX = O_ST + 21072;    // 2 x 3072 (parity)
static constexpr size_t oSCTX = O_ST + 27216;    // 2 x 3072
static constexpr size_t oPREP = O_ST + 33360;    // 2 x 3072
static constexpr size_t oGIA  = O_ST + 39504;    // 18000
static constexpr size_t oGHA  = O_ST + 57504;    // 18000
static constexpr size_t oGID  = O_ST + 75504;    // 9216
static constexpr size_t oGHD  = O_ST + 84720;    // 9216
static constexpr size_t oLACC = O_ST + 93936;    // 8
static constexpr size_t oVLA  = O_ST + 93944;    // 6000
static constexpr size_t oINVN = O_ST + 99944;    // 64
static constexpr size_t oBAR  = O_ST + 100008;   // 4096 u32 (slots + flags)
static constexpr size_t oZ384 = O_ST + 104200;   // 384 zeros (bias for DIB gemm)
static constexpr size_t O_SCR = O_ST + 105000;
// packed gate weights: [K/4][NR][4]  (fp32)
static constexpr size_t oWIHAT_A = O_SCR + 0;         //  96*2250*4 = 864000
static constexpr size_t oWHHT_A  = O_SCR + 864000;    // 188*2250*4 = 1692000
static constexpr size_t oWIHAT_D = O_SCR + 2556000;   //  96*1152*4 = 442368
static constexpr size_t oWHHT_D  = O_SCR + 2998368;   //  96*1152*4 = 442368
static constexpr size_t oH2AT    = O_SCR + 3440736;   // 750*384
static constexpr size_t oAOT     = O_SCR + 3728736;   // 384*60
static constexpr size_t oEMBT    = O_SCR + 3751776;   // 2048*384
static constexpr size_t oGEA     = O_SCR + 4538208;   // 2048*2250
static constexpr size_t oGED     = O_SCR + 9146208;   // 2048*1152
static constexpr size_t oDIB     = O_SCR + 11505504;  // 64*384 (SPK @ D2AW^T)

// ---------------------------------------------------------------------------
// Generic tiled transpose: out[c*R + r] = in[r*ldin + c]
__global__ void transpose_k(const float* __restrict__ in, int ldin, int R, int C,
                            float* __restrict__ out){
  __shared__ float t[32][33];
  int c0 = blockIdx.x*32, r0 = blockIdx.y*32;
  int x = threadIdx.x, y = threadIdx.y;
  for (int i = y; i < 32; i += 8){
    int r = r0 + i, c = c0 + x;
    t[i][x] = (r < R && c < C) ? in[(size_t)r*ldin + c] : 0.f;
  }
  __syncthreads();
  for (int i = y; i < 32; i += 8){
    int c = c0 + i, r = r0 + x;
    if (c < C && r < R) out[(size_t)c*R + r] = t[x][i];
  }
}

// Pack transposed weights as [ceil(K/4)][R][4]
__global__ void packT_k(const float* __restrict__ in, int ldin, int R, int K,
                        float* __restrict__ out){
  __shared__ float tl[32][33];
  int k0 = blockIdx.x*32, r0 = blockIdx.y*32;
  int x = threadIdx.x, y = threadIdx.y;
  int K4 = ((K + 3) >> 2) << 2;
  for (int i = y; i < 32; i += 8){
    int r = r0 + i, k = k0 + x;
    tl[i][x] = (r < R && k < K) ? in[(size_t)r*ldin + k] : 0.f;
  }
  __syncthreads();
  for (int i = y; i < 32; i += 8){
    int k = k0 + i, r = r0 + x;
    if (k < K4 && r < R) out[((size_t)(k >> 2)*R + r)*4 + (k & 3)] = tl[x][i];
  }
}

// K-transpose for encoder attention
__global__ void kt_k(const float* __restrict__ QKV, float* __restrict__ KT){
  __shared__ float t[32][33];
  int z = blockIdx.z; int b = z >> 2, h = z & 3;
  const float* in = QKV + (size_t)b*L_ENC*1152 + 384 + h*HDIM;
  float* out = KT + (size_t)z*HDIM*L_ENC;
  int c0 = blockIdx.x*32, r0 = blockIdx.y*32;
  int x = threadIdx.x, y = threadIdx.y;
  for (int i = y; i < 32; i += 8){
    int r = r0 + i, c = c0 + x;
    t[i][x] = (r < L_ENC && c < HDIM) ? in[(size_t)r*1152 + c] : 0.f;
  }
  __syncthreads();
  for (int i = y; i < 32; i += 8){
    int c = c0 + i, r = r0 + x;
    if (c < HDIM && r < L_ENC) out[(size_t)c*L_ENC + r] = t[x][i];
  }
}

// ---------------------------------------------------------------------------
// fp32 GEMM, 128x128 tile, BK=16, 256 threads, 8x8 microtile.
// C[M,N] = act(A[M,K] @ W[N,K]^T + bias[N] (+ Res[M,N])).  K % 16 == 0.
template<int RELU, int HASRES>
__global__ __launch_bounds__(256) void gemm_k(
    const float* __restrict__ A, int lda, const float* __restrict__ W, int ldw,
    const float* __restrict__ bias, const float* __restrict__ Res,
    float* __restrict__ C, int ldc, int M, int N, int K)
{
  __shared__ __align__(16) float As[16][132];
  __shared__ __align__(16) float Ws[16][132];
  int tid = threadIdx.x;
  int row0 = blockIdx.y*128, col0 = blockIdx.x*128;
  int tx = tid & 15, ty = tid >> 4;
  int lr = tid >> 1, lk = (tid & 1)*8;
  float acc[8][8] = {};
  int ar = row0 + lr, wr = col0 + lr;
  for (int k0 = 0; k0 < K; k0 += 16){
    float4 a0 = make_float4(0,0,0,0), a1 = make_float4(0,0,0,0);
    float4 w0 = make_float4(0,0,0,0), w1 = make_float4(0,0,0,0);
    if (ar < M){
      const float* ap = A + (size_t)ar*lda + k0 + lk;
      a0 = *(const float4*)ap; a1 = *(const float4*)(ap + 4);
    }
    if (wr < N){
      const float* wp = W + (size_t)wr*ldw + k0 + lk;
      w0 = *(const float4*)wp; w1 = *(const float4*)(wp + 4);
    }
    __syncthreads();
    As[lk+0][lr] = a0.x; As[lk+1][lr] = a0.y; As[lk+2][lr] = a0.z; As[lk+3][lr] = a0.w;
    As[lk+4][lr] = a1.x; As[lk+5][lr] = a1.y; As[lk+6][lr] = a1.z; As[lk+7][lr] = a1.w;
    Ws[lk+0][lr] = w0.x; Ws[lk+1][lr] = w0.y; Ws[lk+2][lr] = w0.z; Ws[lk+3][lr] = w0.w;
    Ws[lk+4][lr] = w1.x; Ws[lk+5][lr] = w1.y; Ws[lk+6][lr] = w1.z; Ws[lk+7][lr] = w1.w;
    __syncthreads();
    #pragma unroll
    for (int k = 0; k < 16; k++){
      float av[8], bv[8];
      *(float4*)&av[0] = *(const float4*)&As[k][ty*8];
      *(float4*)&av[4] = *(const float4*)&As[k][ty*8+4];
      *(float4*)&bv[0] = *(const float4*)&Ws[k][tx*8];
      *(float4*)&bv[4] = *(const float4*)&Ws[k][tx*8+4];
      #pragma unroll
      for (int ii = 0; ii < 8; ii++){
        #pragma unroll
        for (int jj = 0; jj < 8; jj++) acc[ii][jj] += av[ii]*bv[jj];
      }
    }
  }
  #pragma unroll
  for (int ii = 0; ii < 8; ii++){
    int m = row0 + ty*8 + ii;
    if (m >= M) continue;
    #pragma unroll
    for (int jj = 0; jj < 8; jj++){
      int n = col0 + tx*8 + jj;
      if (n >= N) continue;
      float v = acc[ii][jj] + bias[n];
      if (HASRES) v += Res[(size_t)m*ldc + n];
      if (RELU) v = fmaxf(v, 0.f);
      C[(size_t)m*ldc + n] = v;
    }
  }
}

// ---------------------------------------------------------------------------
// im2col for conv1 (k=3, pad=1, stride=1)
__global__ void im2col1(const float* __restrict__ in, float* __restrict__ P){
  int t = blockIdx.x, b = blockIdx.y, i = threadIdx.x;
  if (i >= 240) return;
  int ic = i/3, kt = i - ic*3;
  int p = t + kt - 1;
  P[((size_t)(b*T_AUD + t))*240 + i] = (p >= 0 && p < T_AUD) ? in[((size_t)(b*80 + ic))*T_AUD + p] : 0.f;
}

// im2col for conv2 (k=3, pad=1, stride=2)
__global__ __launch_bounds__(384) void im2col2(const float* __restrict__ X1T, float* __restrict__ P){
  int t = blockIdx.x, b = blockIdx.y, ic = threadIdx.x;
  size_t ob = ((size_t)(b*L_ENC + t))*1152 + (size_t)ic*3;
  #pragma unroll
  for (int kt = 0; kt < 3; kt++){
    int p = 2*t + kt - 1;
    P[ob + kt] = (p >= 0 && p < T_AUD) ? X1T[((size_t)(b*T_AUD + p))*DD + ic] : 0.f;
  }
}

// Vectorized dup (rocclr D2D blit is ~serial)
__global__ __launch_bounds__(256) void dup_k(const float* __restrict__ src,
    float* __restrict__ a, float* __restrict__ b){
  size_t i = (size_t)blockIdx.x*256 + threadIdx.x;
  float4 v = ((const float4*)src)[i];
  ((float4*)a)[i] = v;
  ((float4*)b)[i] = v;
}

// ---------------------------------------------------------------------------
// LayerNorm in-place over rows of 384
__global__ __launch_bounds__(128) void ln_k(float* __restrict__ X, const float* __restrict__ g,
                                            const float* __restrict__ bt){
  int r = blockIdx.x, tid = threadIdx.x;
  float* p = X + (size_t)r*DD;
  float v0 = p[tid], v1 = p[tid+128], v2 = p[tid+256];
  __shared__ float red[128];
  red[tid] = v0+v1+v2; __syncthreads();
  for (int k = 64; k > 0; k >>= 1){ if (tid < k) red[tid] += red[tid+k]; __syncthreads(); }
  float m = red[0] * (1.f/384.f);
  __syncthreads();
  float d0 = v0-m, d1 = v1-m, d2 = v2-m;
  red[tid] = d0*d0 + d1*d1 + d2*d2; __syncthreads();
  for (int k = 64; k > 0; k >>= 1){ if (tid < k) red[tid] += red[tid+k]; __syncthreads(); }
  float rs = rsqrtf(red[0]*(1.f/384.f) + 1e-5f);
  p[tid]     = d0*rs*g[tid]     + bt[tid];
  p[tid+128] = d1*rs*g[tid+128] + bt[tid+128];
  p[tid+256] = d2*rs*g[tid+256] + bt[tid+256];
}

// ---------------------------------------------------------------------------
// Encoder attention, fused scores+softmax+AV. 16 rows per block (wave per row).
__global__ __launch_bounds__(1024) void attn_enc(const float* __restrict__ QKV,
    const float* __restrict__ KT, float* __restrict__ ctx){
  int b = blockIdx.z, h = blockIdx.y, i0 = blockIdx.x*16;
  int tid = threadIdx.x, lane = tid & 63, wv = tid >> 6;
  __shared__ float q_s[16][96];
  __shared__ float p_s[16][752];
  __shared__ float den_s[16];
  for (int idx = tid; idx < 16*96; idx += 1024){
    int r2 = idx/96, c = idx - r2*96; int i = i0 + r2;
    q_s[r2][c] = (i < L_ENC) ? QKV[((size_t)(b*L_ENC + i))*1152 + h*HDIM + c]*0.10206207f : 0.f;
  }
  __syncthreads();
  int i = i0 + wv;
  const float* ktb = KT + ((size_t)(b*4 + h))*HDIM*L_ENC;
  if (i < L_ENC){
    float sr[12] = {0,0,0,0,0,0,0,0,0,0,0,0};
    for (int c = 0; c < 96; c++){
      float qc = q_s[wv][c];
      const float* kr = ktb + c*L_ENC + lane;
      #pragma unroll
      for (int jt = 0; jt < 12; jt++) sr[jt] += qc*kr[jt*64];
    }
    float mx = -1e30f;
    #pragma unroll
    for (int jt = 0; jt < 12; jt++){ if (lane + jt*64 < L_ENC) mx = fmaxf(mx, sr[jt]); }
    #pragma unroll
    for (int o = 32; o > 0; o >>= 1) mx = fmaxf(mx, __shfl_xor(mx, o));
    float den = 0.f;
    #pragma unroll
    for (int jt = 0; jt < 12; jt++){
      int j = lane + jt*64;
      if (j < L_ENC){ float e = __expf(sr[jt]-mx); p_s[wv][j] = e; den += e; }
    }
    #pragma unroll
    for (int o = 32; o > 0; o >>= 1) den += __shfl_xor(den, o);
    if (lane == 0) den_s[wv] = den;
  }
  __syncthreads();
  if (i < L_ENC){
    float idn = 1.f/den_s[wv];
    const float* vb = QKV + (size_t)b*L_ENC*1152 + 768 + h*HDIM;
    float a0 = 0.f, a1 = 0.f;
    for (int j = 0; j < L_ENC; j++){
      float pj = p_s[wv][j];
      const float* vr = vb + (size_t)j*1152;
      a0 += pj*vr[lane];
      if (lane < 32) a1 += pj*vr[lane + 64];
    }
    size_t ob = ((size_t)(b*L_ENC + i))*DD + h*HDIM;
    ctx[ob + lane] = a0*idn;
    if (lane < 32) ctx[ob + lane + 64] = a1*idn;
  }
}

// ---------------------------------------------------------------------------
// Decode precompute helpers
__global__ __launch_bounds__(384) void embed_k(const float* __restrict__ emb,
    const int* __restrict__ tgtA, float* __restrict__ E){
  int row = blockIdx.x; int t = row >> 3, b = row & 7;
  int tok = 0;
  if (t > 0){ int v = tgtA[b*T_TXT + t - 1]; tok = (v == -100) ? 0 : v; }
  E[(size_t)row*DD + threadIdx.x] = emb[(size_t)tok*DD + threadIdx.x];
}

__global__ __launch_bounds__(256) void vla_k(const float* __restrict__ EA,
    const float* __restrict__ lav, const float* __restrict__ lain, float* __restrict__ VLA){
  int row = blockIdx.x*4 + (threadIdx.x >> 6);
  int lane = threadIdx.x & 63;
  if (row >= BB*L_ENC) return;
  const float* p = EA + (size_t)row*DD;
  float s = 0.f;
  for (int d = lane; d < DD; d += 64) s += p[d]*lav[d];
  #pragma unroll
  for (int o = 32; o > 0; o >>= 1) s += __shfl_xor(s, o);
  if (lane == 0) VLA[row] = s + lain[2];
}

__global__ void invn_k(const float* __restrict__ inv, float* __restrict__ INVN){
  int row = blockIdx.x; int lane = threadIdx.x;
  float s = 0.f;
  for (int d = lane; d < DD; d += 64){ float v = inv[(size_t)row*DD + d]; s += v*v; }
  #pragma unroll
  for (int o = 32; o > 0; o >>= 1) s += __shfl_xor(s, o);
  if (lane == 0) INVN[row] = sqrtf(s);
}

// ---------------------------------------------------------------------------
struct DecParams {
  float* ws; float* out;
  const float* ABHH; const float* DBHH;
  const float* SPK;  const float* AOB;
  const float* LAQ; const float* LAK; const float* LAIB; const float* LAOW; const float* LAOB;
  const float* H2AB; const float* D2AB;
  const int* TGTA; const int* TGTD;
};

// Grid barrier: distributed arrival slots + distributed broadcast flags.
static __device__ __forceinline__ void gbar(unsigned* s, unsigned epoch){
  __syncthreads();
  int tid = threadIdx.x;
  if (blockIdx.x == 0){
    if (tid > 0 && tid < NB){
      while (__hip_atomic_load(&s[tid*4], __ATOMIC_RELAXED, __HIP_MEMORY_SCOPE_AGENT) < epoch)
        __builtin_amdgcn_s_sleep(4);
    }
    __syncthreads();
    if (tid < NB)
      __hip_atomic_store(&s[(512 + tid)*4], epoch, __ATOMIC_RELAXED, __HIP_MEMORY_SCOPE_AGENT);
  } else {
    if (tid == 0){
      __hip_atomic_store(&s[blockIdx.x*4], epoch, __ATOMIC_RELAXED, __HIP_MEMORY_SCOPE_AGENT);
      while (__hip_atomic_load(&s[(512 + blockIdx.x)*4], __ATOMIC_RELAXED, __HIP_MEMORY_SCOPE_AGENT) < epoch)
        __builtin_amdgcn_s_sleep(4);
    }
    __syncthreads();
  }
}

// NOTE: macro params must NOT be named after vector members (w/x/y/z).
#define FMA8(acc, s_, base) { const float4 b0_ = *(const float4*)&(base)[0]; const float4 b1_ = *(const float4*)&(base)[4]; \
  acc[0]+=b0_.x*(s_); acc[1]+=b0_.y*(s_); acc[2]+=b0_.z*(s_); acc[3]+=b0_.w*(s_); \
  acc[4]+=b1_.x*(s_); acc[5]+=b1_.y*(s_); acc[6]+=b1_.z*(s_); acc[7]+=b1_.w*(s_); }

// GRU gate pre-activations, one 16-row task per block, 512 thr = 32 k-partitions.
// Weights packed [K/4][NR][4] -> float4 loads.  [R7 verbatim]
template<int NR, int KH, int KQH>
__device__ void gates_fn(int task, const float* __restrict__ WIT, const float* __restrict__ WHT,
                         const float* __restrict__ ctxv, const float* __restrict__ hv,
                         const float* __restrict__ GE, const float* __restrict__ bhh,
                         float* __restrict__ GI, float* __restrict__ GH, int t, float* SM)
{
  float* ac  = SM;                  // [96 quads][32]
  float* hh  = SM + 3072;           // [KQH quads][32]
  float* pgi = SM + 3072 + KQH*32;  // [32][16][8]
  float* pgh = pgi + 4096;
  int tid = threadIdx.x;
  for (int idx = tid; idx < 3072; idx += TB){ int b = idx/384, k = idx - b*384; ac[k*8+b] = cld(&ctxv[idx]); }
  for (int idx = tid; idx < KH*8;  idx += TB){ int b = idx/KH,  k = idx - b*KH;  hh[k*8+b] = cld(&hv[idx]); }
  for (int idx = KH*8 + tid; idx < KQH*32; idx += TB) hh[idx] = 0.f;
  __syncthreads();
  int rl = tid & 15, kp = tid >> 4;   // 32 k-partitions
  int r = task*16 + rl;
  float gi[8] = {}, gh[8] = {};
  if (r < NR){
    const float4* W4 = (const float4*)WIT;
    int q0 = (kp*96) >> 5, q1 = ((kp+1)*96) >> 5;
    for (int q = q0; q < q1; q++){
      float4 w4 = W4[(size_t)q*NR + r];
      const float* a = &ac[q*32];
      FMA8(gi, w4.x, a+0); FMA8(gi, w4.y, a+8); FMA8(gi, w4.z, a+16); FMA8(gi, w4.w, a+24);
    }
    const float4* WH4 = (const float4*)WHT;
    int h0 = (kp*KQH) >> 5, h1 = ((kp+1)*KQH) >> 5;
    for (int q = h0; q < h1; q++){
      float4 w4 = WH4[(size_t)q*NR + r];
      const float* a = &hh[q*32];
      FMA8(gh, w4.x, a+0); FMA8(gh, w4.y, a+8); FMA8(gh, w4.z, a+16); FMA8(gh, w4.w, a+24);
    }
  }
  #pragma unroll
  for (int b = 0; b < 8; b++){ pgi[(kp*16+rl)*8 + b] = gi[b]; pgh[(kp*16+rl)*8 + b] = gh[b]; }
  __syncthreads();
  if (tid < 128){
    int rl2 = tid & 15, bb = tid >> 4;
    int rr = task*16 + rl2;
    if (rr < NR){
      float s1 = 0.f, s2 = 0.f;
      #pragma unroll
      for (int kq = 0; kq < 32; kq++){ s1 += pgi[(kq*16+rl2)*8+bb]; s2 += pgh[(kq*16+rl2)*8+bb]; }
      cst(&GI[(size_t)bb*NR + rr], s1 + GE[((size_t)t*8 + bb)*NR + rr]);
      cst(&GH[(size_t)bb*NR + rr], s2 + bhh[rr]);
    }
  }
  __syncthreads();
}

// Phase A worker: asr GRU combine + rank-1 attention + fused ctx accumulation.
// 232 blocks, chunk-major: b = bid&7, chunk = bid>>3.  [R7 verbatim]
__device__ void phase_hattn_ctx(int bid, int t, float* ws, const DecParams& P, float* SM)
{
  float* kk = SM;            // 768
  float* vv = SM + 768;      // 768
  float* wl = SM + 1536;     // 32
  float* hl = SM + 1568;     // 32
  float* part = SM + 1600;   // 5*96*12 = 5760
  int tid = threadIdx.x;
  int b = bid & 7, chunk = bid >> 3;
  int i0 = chunk*26; int n = L_ENC - i0; if (n > 26) n = 26;
  const float* acur = ws + ((t & 1) ? oATT1 : oATT0);
  float*       anxt = ws + ((t & 1) ? oATT0 : oATT1);
  const float* GIAp = ws + oGIA; const float* GHAp = ws + oGHA;
  float* HASRp = ws + oHASR;
  const float* VLAp = ws + oVLA;
  float kw = P.LAK[0], kb = P.LAIB[1];
  for (int j = tid; j < L_ENC; j += TB){
    kk[j] = cld(&acur[b*L_ENC + j])*kw + kb;
    vv[j] = VLAp[b*L_ENC + j];
  }
  __syncthreads();
  int wv = tid >> 6, lane = tid & 63;
  float laq = P.LAQ[0], li0 = P.LAIB[0], low = P.LAOW[0], lob = P.LAOB[0];
  for (int il = wv; il < n; il += 8){
    int i = i0 + il;
    int base = b*2250 + i;
    float rr = sigmf(cld(&GIAp[base]) + cld(&GHAp[base]));
    float zz = sigmf(cld(&GIAp[base+750]) + cld(&GHAp[base+750]));
    float nn = tanhf(cld(&GIAp[base+1500]) + rr*cld(&GHAp[base+1500]));
    float h = (1.f - zz)*nn + zz*cld(&HASRp[b*L_ENC + i]);
    float q = h*laq + li0;
    float sr[12]; float mx = -1e30f;
    #pragma unroll
    for (int jt = 0; jt < 12; jt++){
      int j = lane + jt*64;
      float s = (j < L_ENC) ? q*kk[j] : -1e30f;
      sr[jt] = s; mx = fmaxf(mx, s);
    }
    #pragma unroll
    for (int o = 32; o > 0; o >>= 1) mx = fmaxf(mx, __shfl_xor(mx, o));
    float se = 0.f, sv = 0.f;
    #pragma unroll
    for (int jt = 0; jt < 12; jt++){
      int j = lane + jt*64;
      if (j < L_ENC){ float e = __expf(sr[jt] - mx); se += e; sv += e*vv[j]; }
    }
    #pragma unroll
    for (int o = 32; o > 0; o >>= 1){ se += __shfl_xor(se, o); sv += __shfl_xor(sv, o); }
    if (lane == 0){
      cst(&HASRp[b*L_ENC + i], h);
      float w = (sv/se)*low + lob;
      cst(&anxt[b*L_ENC + i], w);
      wl[il] = w; hl[il] = h;
    }
  }
  __syncthreads();
  // ctx partials: 480 threads = 5 l-groups x 96 d-quads, float4 loads
  if (tid < 480){
    int lg = tid / 96, dq = tid - lg*96;
    int d0 = dq*4;
    const float* EAb = ws + O_EA + (size_t)b*L_ENC*DD + d0;
    const float* EDb = ws + O_ED + (size_t)b*L_ENC*DD + d0;
    const float* H2b = ws + oH2AT + d0;
    float4 a4 = {0,0,0,0}, s4 = {0,0,0,0}, h4 = {0,0,0,0};
    for (int j = lg; j < n; j += 5){
      size_t lo = (size_t)(i0 + j)*DD;
      float wj = wl[j], hj = hl[j];
      float4 e = *(const float4*)(EAb + lo);
      a4.x += e.x*wj; a4.y += e.y*wj; a4.z += e.z*wj; a4.w += e.w*wj;
      float4 e2 = *(const float4*)(EDb + lo);
      s4.x += e2.x*wj; s4.y += e2.y*wj; s4.z += e2.z*wj; s4.w += e2.w*wj;
      float4 e3 = *(const float4*)(H2b + lo);
      h4.x += e3.x*hj; h4.y += e3.y*hj; h4.z += e3.z*hj; h4.w += e3.w*hj;
    }
    float* pp = part + (size_t)tid*12;
    *(float4*)pp = a4; *(float4*)(pp+4) = s4; *(float4*)(pp+8) = h4;
  }
  __syncthreads();
  if (tid < 96){
    float4 ra = {0,0,0,0}, rs = {0,0,0,0}, rh = {0,0,0,0};
    #pragma unroll
    for (int g = 0; g < 5; g++){
      const float* pp = part + (size_t)(g*96 + tid)*12;
      float4 pa = *(const float4*)pp, ps = *(const float4*)(pp+4), ph = *(const float4*)(pp+8);
      ra.x += pa.x; ra.y += pa.y; ra.z += pa.z; ra.w += pa.w;
      rs.x += ps.x; rs.y += ps.y; rs.z += ps.z; rs.w += ps.w;
      rh.x += ph.x; rh.y += ph.y; rh.z += ph.z; rh.w += ph.w;
    }
    int par = t & 1;
    int d0 = tid*4;
    float* A = &ws[oACTX + par*3072 + b*DD + d0];
    float* S = &ws[oSCTX + par*3072 + b*DD + d0];
    float* Pr = &ws[oPREP + par*3072 + b*DD + d0];
    atomicAdd(&A[0], ra.x); atomicAdd(&A[1], ra.y); atomicAdd(&A[2], ra.z); atomicAdd(&A[3], ra.w);
    atomicAdd(&S[0], rs.x); atomicAdd(&S[1], rs.y); atomicAdd(&S[2], rs.z); atomicAdd(&S[3], rs.w);
    atomicAdd(&Pr[0], ra.x+rh.x); atomicAdd(&Pr[1], ra.y+rh.y);
    atomicAdd(&Pr[2], ra.z+rh.z); atomicAdd(&Pr[3], ra.w+rh.w);
  }
  __syncthreads();
}

// Phase: diar GRU combine + speaker softmax + logits + loss. One block per b.
// d2a(spk_state) folded via DIB = SPK @ D2AW^T.  [R7 verbatim]
__device__ void phase_final(int b, int t, float* ws, const float* prep,
                            const DecParams& P, float* SM)
{
  float* hd_s = SM;            // 384
  float* pre_s = SM + 384;     // 384
  float* red = SM + 768;       // 512
  float* beta_s = SM + 1280;   // 8
  float* sc_s = SM + 1288;     // 8
  float* part2 = SM + 1296;    // 8*64
  int tid = threadIdx.x;
  bool act = tid < DD;
  const float* GIDp = ws + oGID; const float* GHDp = ws + oGHD;
  float* HDp = ws + oHD;
  float h = 0.f;
  if (act){
    int base = b*1152 + tid;
    float rr = sigmf(cld(&GIDp[base]) + cld(&GHDp[base]));
    float zz = sigmf(cld(&GIDp[base+384]) + cld(&GHDp[base+384]));
    float nn = tanhf(cld(&GIDp[base+768]) + rr*cld(&GHDp[base+768]));
    h = (1.f - zz)*nn + zz*cld(&HDp[b*DD + tid]);
    hd_s[tid] = h; cst(&HDp[b*DD + tid], h);
  }
  red[tid] = act ? h*h : 0.f;
  __syncthreads();
  for (int s = 256; s > 0; s >>= 1){ if (tid < s) red[tid] += red[tid+s]; __syncthreads(); }
  float hn = sqrtf(red[0]);
  int sg = tid >> 6, lane = tid & 63;
  float ps = 0.f;
  for (int j = lane; j < DD; j += 64) ps += P.SPK[((size_t)(b*8 + sg))*DD + j]*hd_s[j];
  #pragma unroll
  for (int o = 32; o > 0; o >>= 1) ps += __shfl_xor(ps, o);
  if (lane == 0) sc_s[sg] = ps / (hn * ws[oINVN + b*8 + sg]);
  __syncthreads();
  if (tid == 0){
    float mx = -1e30f;
    for (int s2 = 0; s2 < 8; s2++) mx = fmaxf(mx, sc_s[s2]);
    float sm = 0.f;
    for (int s2 = 0; s2 < 8; s2++){ float e = __expf(sc_s[s2] - mx); beta_s[s2] = e; sm += e; }
    float isv = 1.f/sm;
    for (int s2 = 0; s2 < 8; s2++) beta_s[s2] *= isv;
    int td = P.TGTD[b*T_TXT + t];
    if (td != -100){ atomicAdd(&ws[oLACC+2], beta_s[td]); atomicAdd(&ws[oLACC+3], 1.f); }
  }
  __syncthreads();
  if (tid < 8) P.out[122880 + ((size_t)(b*T_TXT + t))*8 + tid] = beta_s[tid];
  if (act){
    float p = cld(&prep[b*DD + tid]);
    const float* Mb = ws + oDIB + (size_t)(b*8)*DD + tid;
    #pragma unroll
    for (int s2 = 0; s2 < 8; s2++) p += beta_s[s2]*Mb[(size_t)s2*DD];
    pre_s[tid] = p;
  }
  __syncthreads();
  {
    int vg = tid >> 6, v = tid & 63;
    float pl = 0.f;
    if (v < VOCAB){
      const float* AOTp = ws + oAOT;
      int d0 = vg*48;
      for (int d2 = d0; d2 < d0+48; d2++) pl += pre_s[d2]*AOTp[d2*VOCAB + v];
    }
    part2[vg*64 + v] = pl;
  }
  __syncthreads();
  if (tid < VOCAB){
    float lg = P.AOB[tid];
    #pragma unroll
    for (int g = 0; g < 8; g++) lg += part2[g*64 + tid];
    P.out[((size_t)(b*T_TXT + t))*VOCAB + tid] = lg;
    int ta = P.TGTA[b*T_TXT + t];
    if (ta == tid) atomicAdd(&ws[oLACC+0], lg);
    if (tid == 0 && ta != -100) atomicAdd(&ws[oLACC+1], 1.f);
  }
  __syncthreads();
}

// Persistent decode loop (480 blocks, 2/CU), 2 barriers per step.  [R7 verbatim]
// A: hattn+ctx(t)[0..231] || final(t-1)[232..239]
// B: gates_D(t)[0..71] || gates_A(t+1)[72..212] || init(t+1)[213..220]
__global__ __launch_bounds__(TB, 4) void dec_loop(DecParams P)
{
  __shared__ __align__(16) float SM[17280];   // 69.1 KB
  int bid = blockIdx.x;
  float* ws = P.ws;
  unsigned* slots = (unsigned*)(ws + oBAR);
  unsigned ep = 0;

  // prologue: asr gates(0) (ACTX[par0]=HASR=0 from memset) + PREP[par0] base
  if (bid < 141)
    gates_fn<2250,750,188>(bid, ws+oWIHAT_A, ws+oWHHT_A, ws+oACTX, ws+oHASR,
                           ws+oGEA, P.ABHH, ws+oGIA, ws+oGHA, 0, SM);
  else if (bid < 149){
    int b = bid - 141;
    for (int d = threadIdx.x; d < DD; d += TB)
      cst(&ws[oPREP + b*DD + d], P.H2AB[d] + P.D2AB[d]);
  }
  gbar(slots, ++ep);

  for (int t = 0; t <= T_TXT; t++){
    // ---- Phase A ----
    if (t < T_TXT && bid < 232) phase_hattn_ctx(bid, t, ws, P, SM);
    else if (bid >= 232 && bid < 240 && t >= 1)
      phase_final(bid - 232, t - 1, ws, ws + oPREP + ((t-1) & 1)*3072, P, SM);
    gbar(slots, ++ep);
    if (t == T_TXT) break;

    // ---- Phase B ----
    if (bid < 72)
      gates_fn<1152,384,96>(bid, ws+oWIHAT_D, ws+oWHHT_D, ws+oSCTX+(t&1)*3072, ws+oHD,
                            ws+oGED, P.DBHH, ws+oGID, ws+oGHD, t, SM);
    else if (bid < 213){
      if (t + 1 < T_TXT)
        gates_fn<2250,750,188>(bid-72, ws+oWIHAT_A, ws+oWHHT_A, ws+oACTX+(t&1)*3072, ws+oHASR,
                               ws+oGEA, P.ABHH, ws+oGIA, ws+oGHA, t+1, SM);
    } else if (bid < 221 && t + 1 < T_TXT){
      int b = bid - 213, par = (t + 1) & 1;
      for (int d = threadIdx.x; d < DD; d += TB){
        cst(&ws[oACTX + par*3072 + b*DD + d], 0.f);
        cst(&ws[oSCTX + par*3072 + b*DD + d], 0.f);
        cst(&ws[oPREP + par*3072 + b*DD + d], P.H2AB[d] + P.D2AB[d]);
      }
    }
    gbar(slots, ++ep);
  }
}

__global__ void loss_final_k(const float* __restrict__ lacc, float* __restrict__ out){
  if (threadIdx.x == 0 && blockIdx.x == 0){
    float la = lacc[0]/fmaxf(lacc[1], 1.f);
    float ld = lacc[2]/fmaxf(lacc[3], 1.f);
    out[139264] = -(la + ld);
  }
}

// ---------------------------------------------------------------------------
extern "C" void kernel_launch(void* const* d_in, const int* in_sizes, int n_in,
                              void* d_out, int out_size, void* d_ws, size_t ws_size,
                              hipStream_t stream)
{
  (void)in_sizes; (void)n_in; (void)out_size; (void)ws_size;
  float* ws  = (float*)d_ws;
  float* out = (float*)d_out;

  const float* IN0   = (const float*)d_in[0];
  const float* SPK   = (const float*)d_in[1];
  const float* C1W   = (const float*)d_in[2];
  const float* C1B   = (const float*)d_in[3];
  const float* C2W   = (const float*)d_in[4];
  const float* C2B   = (const float*)d_in[5];
  const float* LAQ   = (const float*)d_in[30];
  const float* LAK   = (const float*)d_in[31];
  const float* LAV   = (const float*)d_in[32];
  const float* LAIB  = (const float*)d_in[33];
  const float* LAOW  = (const float*)d_in[34];
  const float* LAOB  = (const float*)d_in[35];
  const float* EMB   = (const float*)d_in[36];
  const float* AWIH  = (const float*)d_in[37];
  const float* AWHH  = (const float*)d_in[38];
  const float* ABIH  = (const float*)d_in[39];
  const float* ABHH  = (const float*)d_in[40];
  const float* DWIH  = (const float*)d_in[41];
  const float* DWHH  = (const float*)d_in[42];
  const float* DBIH  = (const float*)d_in[43];
  const float* DBHH  = (const float*)d_in[44];
  const float* AOW   = (const float*)d_in[45];
  const float* AOB   = (const float*)d_in[46];
  const float* D2AW  = (const float*)d_in[47];
  const float* D2AB  = (const float*)d_in[48];
  const float* H2AW  = (const float*)d_in[49];
  const float* H2AB  = (const float*)d_in[50];
  const int*   TGTA  = (const int*)d_in[51];
  const int*   TGTD  = (const int*)d_in[52];

  // encoder scratch overlay (float offsets, relative to ws)
  const size_t S_QKV = O_SCR;
  const size_t S_KT  = O_SCR + 6912000;
  const size_t S_CTX = O_SCR + 9216000;
  const size_t S_Y   = O_SCR + 11520000;
  const size_t S_H   = O_SCR + 13824000;
  const size_t X1T   = S_KT;
  const size_t Pc1   = S_H;
  const size_t Pc2   = S_QKV;

  // 1) zero decode state + loss accumulators + barrier slots/flags + zero-bias
  hipMemsetAsync((void*)(ws + O_ST), 0, 105000*sizeof(float), stream);

  // 2) convs via im2col + GEMM
  im2col1<<<dim3(1500,8), 256, 0, stream>>>(IN0, ws + Pc1);
  gemm_k<1,0><<<dim3(3,94), 256, 0, stream>>>(ws+Pc1, 240, C1W, 240, C1B, nullptr, ws+X1T, 384, 12000, 384, 240);
  im2col2<<<dim3(750,8), 384, 0, stream>>>(ws+X1T, ws+Pc2);
  gemm_k<1,0><<<dim3(3,47), 256, 0, stream>>>(ws+Pc2, 1152, C2W, 1152, C2B, nullptr, ws+O_X, 384, 6000, 384, 1152);

  dup_k<<<2250, 256, 0, stream>>>(ws+O_X, ws+O_EA, ws+O_ED);

  // 3) encoder stacks
  auto enc_layer = [&](float* Xb, const float* qw, const float* qb, const float* ow,
                       const float* ob, const float* f1w, const float* f1b,
                       const float* f2w, const float* f2b,
                       const float* g1, const float* b1, const float* g2, const float* b2){
    gemm_k<0,0><<<dim3(9,47), 256, 0, stream>>>(Xb, 384, qw, 384, qb, nullptr, ws+S_QKV, 1152, 6000, 1152, 384);
    kt_k<<<dim3(3,24,32), dim3(32,8), 0, stream>>>(ws+S_QKV, ws+S_KT);
    attn_enc<<<dim3(47,4,8), 1024, 0, stream>>>(ws+S_QKV, ws+S_KT, ws+S_CTX);
    gemm_k<0,1><<<dim3(3,47), 256, 0, stream>>>(ws+S_CTX, 384, ow, 384, ob, Xb, ws+S_Y, 384, 6000, 384, 384);
    ln_k<<<6000, 128, 0, stream>>>(ws+S_Y, g1, b1);
    gemm_k<1,0><<<dim3(8,47), 256, 0, stream>>>(ws+S_Y, 384, f1w, 384, f1b, nullptr, ws+S_H, 1024, 6000, 1024, 384);
    gemm_k<0,1><<<dim3(3,47), 256, 0, stream>>>(ws+S_H, 1024, f2w, 1024, f2b, ws+S_Y, Xb, 384, 6000, 384, 1024);
    ln_k<<<6000, 128, 0, stream>>>(Xb, g2, b2);
  };
  for (int st = 0; st < 2; st++){
    int base = (st == 0) ? 6 : 18;
    float* Xb = ws + ((st == 0) ? O_EA : O_ED);
    const float* qkvw = (const float*)d_in[base+0];
    const float* qkvb = (const float*)d_in[base+1];
    const float* aow  = (const float*)d_in[base+2];
    const float* aob2 = (const float*)d_in[base+3];
    const float* f1w  = (const float*)d_in[base+4];
    const float* f1b  = (const float*)d_in[base+5];
    const float* f2w  = (const float*)d_in[base+6];
    const float* f2b  = (const float*)d_in[base+7];
    const float* g1   = (const float*)d_in[base+8];
    const float* b1   = (const float*)d_in[base+9];
    const float* g2   = (const float*)d_in[base+10];
    const float* b2   = (const float*)d_in[base+11];
    for (int l = 0; l < 2; l++){
      enc_layer(Xb, qkvw + (size_t)l*1152*384, qkvb + (size_t)l*1152,
                aow + (size_t)l*384*384, aob2 + (size_t)l*384,
                f1w + (size_t)l*1024*384, f1b + (size_t)l*1024,
                f2w + (size_t)l*384*1024, f2b + (size_t)l*384,
                g1 + (size_t)l*384, b1 + (size_t)l*384, g2 + (size_t)l*384, b2 + (size_t)l*384);
    }
  }

  // 4) decode precompute (overlays encoder scratch; runs after encoder done)
  packT_k<<<dim3(12,71), dim3(32,8), 0, stream>>>(AWIH, 768, 2250, 384, ws+oWIHAT_A);
  packT_k<<<dim3(24,71), dim3(32,8), 0, stream>>>(AWHH, 750, 2250, 750, ws+oWHHT_A);
  packT_k<<<dim3(12,36), dim3(32,8), 0, stream>>>(DWIH, 768, 1152, 384, ws+oWIHAT_D);
  packT_k<<<dim3(12,36), dim3(32,8), 0, stream>>>(DWHH, 384, 1152, 384, ws+oWHHT_D);
  transpose_k<<<dim3(24,12), dim3(32,8), 0, stream>>>(H2AW, 750, 384, 750, ws+oH2AT);
  transpose_k<<<dim3(12,2),  dim3(32,8), 0, stream>>>(AOW, 384, 60, 384, ws+oAOT);
  embed_k<<<2048, 384, 0, stream>>>(EMB, TGTA, ws+oEMBT);
  gemm_k<0,0><<<dim3(18,16), 256, 0, stream>>>(ws+oEMBT, 384, AWIH+384, 768, ABIH, nullptr, ws+oGEA, 2250, 2048, 2250, 384);
  gemm_k<0,0><<<dim3(9,16), 256, 0, stream>>>(ws+oEMBT, 384, DWIH+384, 768, DBIH, nullptr, ws+oGED, 1152, 2048, 1152, 384);
  // DIB = SPK(64x384) @ D2AW^T -> [64][384], zero bias
  gemm_k<0,0><<<dim3(3,1), 256, 0, stream>>>(SPK, 384, D2AW, 384, ws+oZ384, nullptr, ws+oDIB, 384, 64, 384, 384);
  vla_k<<<1500, 256, 0, stream>>>(ws+O_EA, LAV, LAIB, ws+oVLA);
  invn_k<<<64, 64, 0, stream>>>(SPK, ws+oINVN);

  // 5) persistent decode (480 blocks = 2/CU, 2 barriers/step)  [R7 config]
  DecParams DP;
  DP.ws = ws; DP.out = out;
  DP.ABHH = ABHH; DP.DBHH = DBHH; DP.SPK = SPK; DP.AOB = AOB;
  DP.LAQ = LAQ; DP.LAK = LAK; DP.LAIB = LAIB; DP.LAOW = LAOW; DP.LAOB = LAOB;
  DP.H2AB = H2AB; DP.D2AB = D2AB; DP.TGTA = TGTA; DP.TGTD = TGTD;
  dec_loop<<<dim3(NB), dim3(TB), 0, stream>>>(DP);

  loss_final_k<<<1, 64, 0, stream>>>(ws+oLACC, out);
}

// Round 13
// 19266.373 us; speedup vs baseline: 1.1978x; 1.0703x over previous
//
#include <hip/hip_runtime.h>
#include <math.h>

// ---------------------------------------------------------------------------
// Model constants
#define L_ENC 750
#define T_AUD 1500
#define DD    384
#define FF    1024
#define NHH   4
#define HDIM  96
#define VOCAB 60
#define T_TXT 256
#define BB    8
#define NB    480   // persistent decode grid: 2 blocks/CU, co-resident
#define TB    512   // decode block size (8 waves/block)

static __device__ __forceinline__ float sigmf(float x){ return 1.f/(1.f + __expf(-x)); }

// Coherent (coherence-point) accessors for mutable cross-block state.
static __device__ __forceinline__ float cld(const float* p){
  return __hip_atomic_load(p, __ATOMIC_RELAXED, __HIP_MEMORY_SCOPE_AGENT);
}
static __device__ __forceinline__ void cst(float* p, float v){
  __hip_atomic_store(p, v, __ATOMIC_RELAXED, __HIP_MEMORY_SCOPE_AGENT);
}

// fp32 -> bf16 (RNE)
static __device__ __forceinline__ unsigned short f2bf(float x){
  union { float f; unsigned int u; } c; c.f = x;
  unsigned int u = c.u + 0x7fffu + ((c.u >> 16) & 1u);
  return (unsigned short)(u >> 16);
}

typedef short bf16x8 __attribute__((ext_vector_type(8)));
typedef float f32x4  __attribute__((ext_vector_type(4)));

// ---------------------------------------------------------------------------
// workspace layout (float offsets)  [R12 layout, verbatim]
static constexpr size_t O_X  = 0;
static constexpr size_t O_EA = 2304000;
static constexpr size_t O_ED = 4608000;
static constexpr size_t O_ST = 6912000;
static constexpr size_t oHASR = O_ST + 0;        // 6000
static constexpr size_t oATT0 = O_ST + 6000;     // 6000
static constexpr size_t oATT1 = O_ST + 12000;    // 6000
static constexpr size_t oHD   = O_ST + 18000;    // 3072 (in-place GRU)
static constexpr size_t oACTX = O_ST + 21072;    // 2 x 3072 (parity)
static constexpr size_t oSCTX = O_ST + 27216;    // 2 x 3072
static constexpr size_t oPREP = O_ST + 33360;    // 2 x 3072
static constexpr size_t oGIA  = O_ST + 39504;    // 18000
static constexpr size_t oGHA  = O_ST + 57504;    // 18000
static constexpr size_t oGID  = O_ST + 75504;    // 9216
static constexpr size_t oGHD  = O_ST + 84720;    // 9216
static constexpr size_t oLACC = O_ST + 93936;    // 8
static constexpr size_t oVLA  = O_ST + 93944;    // 6000
static constexpr size_t oINVN = O_ST + 99944;    // 64
static constexpr size_t oBAR  = O_ST + 100008;   // 4096 u32 (slots + flags)
static constexpr size_t oZ384 = O_ST + 104200;   // 384 zeros (bias for DIB gemm)
static constexpr size_t O_SCR = O_ST + 105000;
// packed gate weights: [K/4][NR][4]  (fp32)
static constexpr size_t oWIHAT_A = O_SCR + 0;         //  96*2250*4 = 864000
static constexpr size_t oWHHT_A  = O_SCR + 864000;    // 188*2250*4 = 1692000
static constexpr size_t oWIHAT_D = O_SCR + 2556000;   //  96*1152*4 = 442368
static constexpr size_t oWHHT_D  = O_SCR + 2998368;   //  96*1152*4 = 442368
static constexpr size_t oH2AT    = O_SCR + 3440736;   // 750*384
static constexpr size_t oAOT     = O_SCR + 3728736;   // 384*60
static constexpr size_t oEMBT    = O_SCR + 3751776;   // 2048*384
static constexpr size_t oGEA     = O_SCR + 4538208;   // 2048*2250
static constexpr size_t oGED     = O_SCR + 9146208;   // 2048*1152
static constexpr size_t oDIB     = O_SCR + 11505504;  // 64*384 (SPK @ D2AW^T)

// ---------------------------------------------------------------------------
// Generic tiled transpose: out[c*R + r] = in[r*ldin + c]
__global__ void transpose_k(const float* __restrict__ in, int ldin, int R, int C,
                            float* __restrict__ out){
  __shared__ float t[32][33];
  int c0 = blockIdx.x*32, r0 = blockIdx.y*32;
  int x = threadIdx.x, y = threadIdx.y;
  for (int i = y; i < 32; i += 8){
    int r = r0 + i, c = c0 + x;
    t[i][x] = (r < R && c < C) ? in[(size_t)r*ldin + c] : 0.f;
  }
  __syncthreads();
  for (int i = y; i < 32; i += 8){
    int c = c0 + i, r = r0 + x;
    if (c < C && r < R) out[(size_t)c*R + r] = t[x][i];
  }
}

// Pack transposed weights as [ceil(K/4)][R][4]
__global__ void packT_k(const float* __restrict__ in, int ldin, int R, int K,
                        float* __restrict__ out){
  __shared__ float tl[32][33];
  int k0 = blockIdx.x*32, r0 = blockIdx.y*32;
  int x = threadIdx.x, y = threadIdx.y;
  int K4 = ((K + 3) >> 2) << 2;
  for (int i = y; i < 32; i += 8){
    int r = r0 + i, k = k0 + x;
    tl[i][x] = (r < R && k < K) ? in[(size_t)r*ldin + k] : 0.f;
  }
  __syncthreads();
  for (int i = y; i < 32; i += 8){
    int k = k0 + i, r = r0 + x;
    if (k < K4 && r < R) out[((size_t)(k >> 2)*R + r)*4 + (k & 3)] = tl[x][i];
  }
}

// K-transpose for encoder attention
__global__ void kt_k(const float* __restrict__ QKV, float* __restrict__ KT){
  __shared__ float t[32][33];
  int z = blockIdx.z; int b = z >> 2, h = z & 3;
  const float* in = QKV + (size_t)b*L_ENC*1152 + 384 + h*HDIM;
  float* out = KT + (size_t)z*HDIM*L_ENC;
  int c0 = blockIdx.x*32, r0 = blockIdx.y*32;
  int x = threadIdx.x, y = threadIdx.y;
  for (int i = y; i < 32; i += 8){
    int r = r0 + i, c = c0 + x;
    t[i][x] = (r < L_ENC && c < HDIM) ? in[(size_t)r*1152 + c] : 0.f;
  }
  __syncthreads();
  for (int i = y; i < 32; i += 8){
    int c = c0 + i, r = r0 + x;
    if (c < HDIM && r < L_ENC) out[(size_t)c*L_ENC + r] = t[x][i];
  }
}

// ---------------------------------------------------------------------------
// MFMA GEMM (bf16 inputs, fp32 accum): C[M,N] = act(A[M,K] @ W[N,K]^T + bias
// (+ Res)).  K % 32 == 0.  64x64 tile, 256 thr = 4 waves, wave = 16x64 band.
// Fragment layouts (HW-verified, guide §3): A/B: row|col = lane&15,
// k = (lane>>4)*8 + j;  C/D: col = lane&15, row = (lane>>4)*4 + reg.
template<int RELU, int HASRES>
__global__ __launch_bounds__(256) void gemm_mf(
    const float* __restrict__ A, int lda, const float* __restrict__ W, int ldw,
    const float* __restrict__ bias, const float* __restrict__ Res,
    float* __restrict__ C, int ldc, int M, int N, int K)
{
  __shared__ unsigned short Asl[64][40];   // +8 pad: 80B row stride
  __shared__ unsigned short Wsl[64][40];
  int tid = threadIdx.x;
  int row0 = blockIdx.y*64, col0 = blockIdx.x*64;
  int wv = tid >> 6, lane = tid & 63;
  f32x4 acc0 = {0,0,0,0}, acc1 = {0,0,0,0}, acc2 = {0,0,0,0}, acc3 = {0,0,0,0};
  int lr = tid & 63, lk = (tid >> 6)*8;
  int ar = row0 + lr, wr = col0 + lr;
  const float* ap = A + (size_t)ar*lda + lk;
  const float* wp = W + (size_t)wr*ldw + lk;
  int afr = wv*16 + (lane & 15);
  int bfr = lane & 15;
  int kof = (lane >> 4)*8;
  for (int k0 = 0; k0 < K; k0 += 32){
    float a8[8] = {0,0,0,0,0,0,0,0}, w8[8] = {0,0,0,0,0,0,0,0};
    if (ar < M){
      *(float4*)&a8[0] = *(const float4*)(ap + k0);
      *(float4*)&a8[4] = *(const float4*)(ap + k0 + 4);
    }
    if (wr < N){
      *(float4*)&w8[0] = *(const float4*)(wp + k0);
      *(float4*)&w8[4] = *(const float4*)(wp + k0 + 4);
    }
    __syncthreads();
    #pragma unroll
    for (int j = 0; j < 8; j++){
      Asl[lr][lk + j] = f2bf(a8[j]);
      Wsl[lr][lk + j] = f2bf(w8[j]);
    }
    __syncthreads();
    bf16x8 af = *(const bf16x8*)&Asl[afr][kof];
    bf16x8 b0 = *(const bf16x8*)&Wsl[bfr +  0][kof];
    bf16x8 b1 = *(const bf16x8*)&Wsl[bfr + 16][kof];
    bf16x8 b2 = *(const bf16x8*)&Wsl[bfr + 32][kof];
    bf16x8 b3 = *(const bf16x8*)&Wsl[bfr + 48][kof];
    acc0 = __builtin_amdgcn_mfma_f32_16x16x32_bf16(af, b0, acc0, 0, 0, 0);
    acc1 = __builtin_amdgcn_mfma_f32_16x16x32_bf16(af, b1, acc1, 0, 0, 0);
    acc2 = __builtin_amdgcn_mfma_f32_16x16x32_bf16(af, b2, acc2, 0, 0, 0);
    acc3 = __builtin_amdgcn_mfma_f32_16x16x32_bf16(af, b3, acc3, 0, 0, 0);
  }
  int crow = row0 + wv*16 + (lane >> 4)*4;
  int ccol = col0 + (lane & 15);
  f32x4 av[4] = {acc0, acc1, acc2, acc3};
  #pragma unroll
  for (int c = 0; c < 4; c++){
    int n = ccol + c*16;
    if (n >= N) continue;
    float bs = bias[n];
    #pragma unroll
    for (int j = 0; j < 4; j++){
      int m = crow + j;
      if (m >= M) continue;
      float v = av[c][j] + bs;
      if (HASRES) v += Res[(size_t)m*ldc + n];
      if (RELU) v = fmaxf(v, 0.f);
      C[(size_t)m*ldc + n] = v;
    }
  }
}

// ---------------------------------------------------------------------------
// fp32 vector GEMM, 128x128 tile (for K%32 != 0 and tiny GEMMs).  K % 16 == 0.
template<int RELU, int HASRES>
__global__ __launch_bounds__(256) void gemm_k(
    const float* __restrict__ A, int lda, const float* __restrict__ W, int ldw,
    const float* __restrict__ bias, const float* __restrict__ Res,
    float* __restrict__ C, int ldc, int M, int N, int K)
{
  __shared__ __align__(16) float As[16][132];
  __shared__ __align__(16) float Ws[16][132];
  int tid = threadIdx.x;
  int row0 = blockIdx.y*128, col0 = blockIdx.x*128;
  int tx = tid & 15, ty = tid >> 4;
  int lr = tid >> 1, lk = (tid & 1)*8;
  float acc[8][8] = {};
  int ar = row0 + lr, wr = col0 + lr;
  for (int k0 = 0; k0 < K; k0 += 16){
    float4 a0 = make_float4(0,0,0,0), a1 = make_float4(0,0,0,0);
    float4 w0 = make_float4(0,0,0,0), w1 = make_float4(0,0,0,0);
    if (ar < M){
      const float* ap = A + (size_t)ar*lda + k0 + lk;
      a0 = *(const float4*)ap; a1 = *(const float4*)(ap + 4);
    }
    if (wr < N){
      const float* wp = W + (size_t)wr*ldw + k0 + lk;
      w0 = *(const float4*)wp; w1 = *(const float4*)(wp + 4);
    }
    __syncthreads();
    As[lk+0][lr] = a0.x; As[lk+1][lr] = a0.y; As[lk+2][lr] = a0.z; As[lk+3][lr] = a0.w;
    As[lk+4][lr] = a1.x; As[lk+5][lr] = a1.y; As[lk+6][lr] = a1.z; As[lk+7][lr] = a1.w;
    Ws[lk+0][lr] = w0.x; Ws[lk+1][lr] = w0.y; Ws[lk+2][lr] = w0.z; Ws[lk+3][lr] = w0.w;
    Ws[lk+4][lr] = w1.x; Ws[lk+5][lr] = w1.y; Ws[lk+6][lr] = w1.z; Ws[lk+7][lr] = w1.w;
    __syncthreads();
    #pragma unroll
    for (int k = 0; k < 16; k++){
      float av[8], bv[8];
      *(float4*)&av[0] = *(const float4*)&As[k][ty*8];
      *(float4*)&av[4] = *(const float4*)&As[k][ty*8+4];
      *(float4*)&bv[0] = *(const float4*)&Ws[k][tx*8];
      *(float4*)&bv[4] = *(const float4*)&Ws[k][tx*8+4];
      #pragma unroll
      for (int ii = 0; ii < 8; ii++){
        #pragma unroll
        for (int jj = 0; jj < 8; jj++) acc[ii][jj] += av[ii]*bv[jj];
      }
    }
  }
  #pragma unroll
  for (int ii = 0; ii < 8; ii++){
    int m = row0 + ty*8 + ii;
    if (m >= M) continue;
    #pragma unroll
    for (int jj = 0; jj < 8; jj++){
      int n = col0 + tx*8 + jj;
      if (n >= N) continue;
      float v = acc[ii][jj] + bias[n];
      if (HASRES) v += Res[(size_t)m*ldc + n];
      if (RELU) v = fmaxf(v, 0.f);
      C[(size_t)m*ldc + n] = v;
    }
  }
}

// ---------------------------------------------------------------------------
// im2col for conv1 (k=3, pad=1, stride=1)
__global__ void im2col1(const float* __restrict__ in, float* __restrict__ P){
  int t = blockIdx.x, b = blockIdx.y, i = threadIdx.x;
  if (i >= 240) return;
  int ic = i/3, kt = i - ic*3;
  int p = t + kt - 1;
  P[((size_t)(b*T_AUD + t))*240 + i] = (p >= 0 && p < T_AUD) ? in[((size_t)(b*80 + ic))*T_AUD + p] : 0.f;
}

// im2col for conv2 (k=3, pad=1, stride=2)
__global__ __launch_bounds__(384) void im2col2(const float* __restrict__ X1T, float* __restrict__ P){
  int t = blockIdx.x, b = blockIdx.y, ic = threadIdx.x;
  size_t ob = ((size_t)(b*L_ENC + t))*1152 + (size_t)ic*3;
  #pragma unroll
  for (int kt = 0; kt < 3; kt++){
    int p = 2*t + kt - 1;
    P[ob + kt] = (p >= 0 && p < T_AUD) ? X1T[((size_t)(b*T_AUD + p))*DD + ic] : 0.f;
  }
}

// Vectorized dup (rocclr D2D blit is ~serial)
__global__ __launch_bounds__(256) void dup_k(const float* __restrict__ src,
    float* __restrict__ a, float* __restrict__ b){
  size_t i = (size_t)blockIdx.x*256 + threadIdx.x;
  float4 v = ((const float4*)src)[i];
  ((float4*)a)[i] = v;
  ((float4*)b)[i] = v;
}

// ---------------------------------------------------------------------------
// LayerNorm in-place over rows of 384
__global__ __launch_bounds__(128) void ln_k(float* __restrict__ X, const float* __restrict__ g,
                                            const float* __restrict__ bt){
  int r = blockIdx.x, tid = threadIdx.x;
  float* p = X + (size_t)r*DD;
  float v0 = p[tid], v1 = p[tid+128], v2 = p[tid+256];
  __shared__ float red[128];
  red[tid] = v0+v1+v2; __syncthreads();
  for (int k = 64; k > 0; k >>= 1){ if (tid < k) red[tid] += red[tid+k]; __syncthreads(); }
  float m = red[0] * (1.f/384.f);
  __syncthreads();
  float d0 = v0-m, d1 = v1-m, d2 = v2-m;
  red[tid] = d0*d0 + d1*d1 + d2*d2; __syncthreads();
  for (int k = 64; k > 0; k >>= 1){ if (tid < k) red[tid] += red[tid+k]; __syncthreads(); }
  float rs = rsqrtf(red[0]*(1.f/384.f) + 1e-5f);
  p[tid]     = d0*rs*g[tid]     + bt[tid];
  p[tid+128] = d1*rs*g[tid+128] + bt[tid+128];
  p[tid+256] = d2*rs*g[tid+256] + bt[tid+256];
}

// ---------------------------------------------------------------------------
// Encoder attention, fused scores+softmax+AV. 16 rows per block (wave per row).
__global__ __launch_bounds__(1024) void attn_enc(const float* __restrict__ QKV,
    const float* __restrict__ KT, float* __restrict__ ctx){
  int b = blockIdx.z, h = blockIdx.y, i0 = blockIdx.x*16;
  int tid = threadIdx.x, lane = tid & 63, wv = tid >> 6;
  __shared__ float q_s[16][96];
  __shared__ float p_s[16][752];
  __shared__ float den_s[16];
  for (int idx = tid; idx < 16*96; idx += 1024){
    int r2 = idx/96, c = idx - r2*96; int i = i0 + r2;
    q_s[r2][c] = (i < L_ENC) ? QKV[((size_t)(b*L_ENC + i))*1152 + h*HDIM + c]*0.10206207f : 0.f;
  }
  __syncthreads();
  int i = i0 + wv;
  const float* ktb = KT + ((size_t)(b*4 + h))*HDIM*L_ENC;
  if (i < L_ENC){
    float sr[12] = {0,0,0,0,0,0,0,0,0,0,0,0};
    for (int c = 0; c < 96; c++){
      float qc = q_s[wv][c];
      const float* kr = ktb + c*L_ENC + lane;
      #pragma unroll
      for (int jt = 0; jt < 12; jt++) sr[jt] += qc*kr[jt*64];
    }
    float mx = -1e30f;
    #pragma unroll
    for (int jt = 0; jt < 12; jt++){ if (lane + jt*64 < L_ENC) mx = fmaxf(mx, sr[jt]); }
    #pragma unroll
    for (int o = 32; o > 0; o >>= 1) mx = fmaxf(mx, __shfl_xor(mx, o));
    float den = 0.f;
    #pragma unroll
    for (int jt = 0; jt < 12; jt++){
      int j = lane + jt*64;
      if (j < L_ENC){ float e = __expf(sr[jt]-mx); p_s[wv][j] = e; den += e; }
    }
    #pragma unroll
    for (int o = 32; o > 0; o >>= 1) den += __shfl_xor(den, o);
    if (lane == 0) den_s[wv] = den;
  }
  __syncthreads();
  if (i < L_ENC){
    float idn = 1.f/den_s[wv];
    const float* vb = QKV + (size_t)b*L_ENC*1152 + 768 + h*HDIM;
    float a0 = 0.f, a1 = 0.f;
    for (int j = 0; j < L_ENC; j++){
      float pj = p_s[wv][j];
      const float* vr = vb + (size_t)j*1152;
      a0 += pj*vr[lane];
      if (lane < 32) a1 += pj*vr[lane + 64];
    }
    size_t ob = ((size_t)(b*L_ENC + i))*DD + h*HDIM;
    ctx[ob + lane] = a0*idn;
    if (lane < 32) ctx[ob + lane + 64] = a1*idn;
  }
}

// ---------------------------------------------------------------------------
// Decode precompute helpers
__global__ __launch_bounds__(384) void embed_k(const float* __restrict__ emb,
    const int* __restrict__ tgtA, float* __restrict__ E){
  int row = blockIdx.x; int t = row >> 3, b = row & 7;
  int tok = 0;
  if (t > 0){ int v = tgtA[b*T_TXT + t - 1]; tok = (v == -100) ? 0 : v; }
  E[(size_t)row*DD + threadIdx.x] = emb[(size_t)tok*DD + threadIdx.x];
}

__global__ __launch_bounds__(256) void vla_k(const float* __restrict__ EA,
    const float* __restrict__ lav, const float* __restrict__ lain, float* __restrict__ VLA){
  int row = blockIdx.x*4 + (threadIdx.x >> 6);
  int lane = threadIdx.x & 63;
  if (row >= BB*L_ENC) return;
  const float* p = EA + (size_t)row*DD;
  float s = 0.f;
  for (int d = lane; d < DD; d += 64) s += p[d]*lav[d];
  #pragma unroll
  for (int o = 32; o > 0; o >>= 1) s += __shfl_xor(s, o);
  if (lane == 0) VLA[row] = s + lain[2];
}

__global__ void invn_k(const float* __restrict__ inv, float* __restrict__ INVN){
  int row = blockIdx.x; int lane = threadIdx.x;
  float s = 0.f;
  for (int d = lane; d < DD; d += 64){ float v = inv[(size_t)row*DD + d]; s += v*v; }
  #pragma unroll
  for (int o = 32; o > 0; o >>= 1) s += __shfl_xor(s, o);
  if (lane == 0) INVN[row] = sqrtf(s);
}

// ---------------------------------------------------------------------------
struct DecParams {
  float* ws; float* out;
  const float* ABHH; const float* DBHH;
  const float* SPK;  const float* AOB;
  const float* LAQ; const float* LAK; const float* LAIB; const float* LAOW; const float* LAOB;
  const float* H2AB; const float* D2AB;
  const int* TGTA; const int* TGTD;
};

// Grid barrier: distributed arrival slots + distributed broadcast flags.
static __device__ __forceinline__ void gbar(unsigned* s, unsigned epoch){
  __syncthreads();
  int tid = threadIdx.x;
  if (blockIdx.x == 0){
    if (tid > 0 && tid < NB){
      while (__hip_atomic_load(&s[tid*4], __ATOMIC_RELAXED, __HIP_MEMORY_SCOPE_AGENT) < epoch)
        __builtin_amdgcn_s_sleep(4);
    }
    __syncthreads();
    if (tid < NB)
      __hip_atomic_store(&s[(512 + tid)*4], epoch, __ATOMIC_RELAXED, __HIP_MEMORY_SCOPE_AGENT);
  } else {
    if (tid == 0){
      __hip_atomic_store(&s[blockIdx.x*4], epoch, __ATOMIC_RELAXED, __HIP_MEMORY_SCOPE_AGENT);
      while (__hip_atomic_load(&s[(512 + blockIdx.x)*4], __ATOMIC_RELAXED, __HIP_MEMORY_SCOPE_AGENT) < epoch)
        __builtin_amdgcn_s_sleep(4);
    }
    __syncthreads();
  }
}

// NOTE: macro params must NOT be named after vector members (w/x/y/z).
#define FMA8(acc, s_, base) { const float4 b0_ = *(const float4*)&(base)[0]; const float4 b1_ = *(const float4*)&(base)[4]; \
  acc[0]+=b0_.x*(s_); acc[1]+=b0_.y*(s_); acc[2]+=b0_.z*(s_); acc[3]+=b0_.w*(s_); \
  acc[4]+=b1_.x*(s_); acc[5]+=b1_.y*(s_); acc[6]+=b1_.z*(s_); acc[7]+=b1_.w*(s_); }

// GRU gate pre-activations, one 16-row task per block, 512 thr = 32 k-partitions.
// Weights packed [K/4][NR][4] -> float4 loads.  [R12 verbatim]
template<int NR, int KH, int KQH>
__device__ void gates_fn(int task, const float* __restrict__ WIT, const float* __restrict__ WHT,
                         const float* __restrict__ ctxv, const float* __restrict__ hv,
                         const float* __restrict__ GE, const float* __restrict__ bhh,
                         float* __restrict__ GI, float* __restrict__ GH, int t, float* SM)
{
  float* ac  = SM;                  // [96 quads][32]
  float* hh  = SM + 3072;           // [KQH quads][32]
  float* pgi = SM + 3072 + KQH*32;  // [32][16][8]
  float* pgh = pgi + 4096;
  int tid = threadIdx.x;
  for (int idx = tid; idx < 3072; idx += TB){ int b = idx/384, k = idx - b*384; ac[k*8+b] = cld(&ctxv[idx]); }
  for (int idx = tid; idx < KH*8;  idx += TB){ int b = idx/KH,  k = idx - b*KH;  hh[k*8+b] = cld(&hv[idx]); }
  for (int idx = KH*8 + tid; idx < KQH*32; idx += TB) hh[idx] = 0.f;
  __syncthreads();
  int rl = tid & 15, kp = tid >> 4;   // 32 k-partitions
  int r = task*16 + rl;
  float gi[8] = {}, gh[8] = {};
  if (r < NR){
    const float4* W4 = (const float4*)WIT;
    int q0 = (kp*96) >> 5, q1 = ((kp+1)*96) >> 5;
    for (int q = q0; q < q1; q++){
      float4 w4 = W4[(size_t)q*NR + r];
      const float* a = &ac[q*32];
      FMA8(gi, w4.x, a+0); FMA8(gi, w4.y, a+8); FMA8(gi, w4.z, a+16); FMA8(gi, w4.w, a+24);
    }
    const float4* WH4 = (const float4*)WHT;
    int h0 = (kp*KQH) >> 5, h1 = ((kp+1)*KQH) >> 5;
    for (int q = h0; q < h1; q++){
      float4 w4 = WH4[(size_t)q*NR + r];
      const float* a = &hh[q*32];
      FMA8(gh, w4.x, a+0); FMA8(gh, w4.y, a+8); FMA8(gh, w4.z, a+16); FMA8(gh, w4.w, a+24);
    }
  }
  #pragma unroll
  for (int b = 0; b < 8; b++){ pgi[(kp*16+rl)*8 + b] = gi[b]; pgh[(kp*16+rl)*8 + b] = gh[b]; }
  __syncthreads();
  if (tid < 128){
    int rl2 = tid & 15, bb = tid >> 4;
    int rr = task*16 + rl2;
    if (rr < NR){
      float s1 = 0.f, s2 = 0.f;
      #pragma unroll
      for (int kq = 0; kq < 32; kq++){ s1 += pgi[(kq*16+rl2)*8+bb]; s2 += pgh[(kq*16+rl2)*8+bb]; }
      cst(&GI[(size_t)bb*NR + rr], s1 + GE[((size_t)t*8 + bb)*NR + rr]);
      cst(&GH[(size_t)bb*NR + rr], s2 + bhh[rr]);
    }
  }
  __syncthreads();
}

// Phase A worker: asr GRU combine + rank-1 attention + fused ctx accumulation.
// 232 blocks, chunk-major: b = bid&7, chunk = bid>>3.  [R12 verbatim]
__device__ void phase_hattn_ctx(int bid, int t, float* ws, const DecParams& P, float* SM)
{
  float* kk = SM;            // 768
  float* vv = SM + 768;      // 768
  float* wl = SM + 1536;     // 32
  float* hl = SM + 1568;     // 32
  float* part = SM + 1600;   // 5*96*12 = 5760
  int tid = threadIdx.x;
  int b = bid & 7, chunk = bid >> 3;
  int i0 = chunk*26; int n = L_ENC - i0; if (n > 26) n = 26;
  const float* acur = ws + ((t & 1) ? oATT1 : oATT0);
  float*       anxt = ws + ((t & 1) ? oATT0 : oATT1);
  const float* GIAp = ws + oGIA; const float* GHAp = ws + oGHA;
  float* HASRp = ws + oHASR;
  const float* VLAp = ws + oVLA;
  float kw = P.LAK[0], kb = P.LAIB[1];
  for (int j = tid; j < L_ENC; j += TB){
    kk[j] = cld(&acur[b*L_ENC + j])*kw + kb;
    vv[j] = VLAp[b*L_ENC + j];
  }
  __syncthreads();
  int wv = tid >> 6, lane = tid & 63;
  float laq = P.LAQ[0], li0 = P.LAIB[0], low = P.LAOW[0], lob = P.LAOB[0];
  for (int il = wv; il < n; il += 8){
    int i = i0 + il;
    int base = b*2250 + i;
    float rr = sigmf(cld(&GIAp[base]) + cld(&GHAp[base]));
    float zz = sigmf(cld(&GIAp[base+750]) + cld(&GHAp[base+750]));
    float nn = tanhf(cld(&GIAp[base+1500]) + rr*cld(&GHAp[base+1500]));
    float h = (1.f - zz)*nn + zz*cld(&HASRp[b*L_ENC + i]);
    float q = h*laq + li0;
    float sr[12]; float mx = -1e30f;
    #pragma unroll
    for (int jt = 0; jt < 12; jt++){
      int j = lane + jt*64;
      float s = (j < L_ENC) ? q*kk[j] : -1e30f;
      sr[jt] = s; mx = fmaxf(mx, s);
    }
    #pragma unroll
    for (int o = 32; o > 0; o >>= 1) mx = fmaxf(mx, __shfl_xor(mx, o));
    float se = 0.f, sv = 0.f;
    #pragma unroll
    for (int jt = 0; jt < 12; jt++){
      int j = lane + jt*64;
      if (j < L_ENC){ float e = __expf(sr[jt] - mx); se += e; sv += e*vv[j]; }
    }
    #pragma unroll
    for (int o = 32; o > 0; o >>= 1){ se += __shfl_xor(se, o); sv += __shfl_xor(sv, o); }
    if (lane == 0){
      cst(&HASRp[b*L_ENC + i], h);
      float w = (sv/se)*low + lob;
      cst(&anxt[b*L_ENC + i], w);
      wl[il] = w; hl[il] = h;
    }
  }
  __syncthreads();
  // ctx partials: 480 threads = 5 l-groups x 96 d-quads, float4 loads
  if (tid < 480){
    int lg = tid / 96, dq = tid - lg*96;
    int d0 = dq*4;
    const float* EAb = ws + O_EA + (size_t)b*L_ENC*DD + d0;
    const float* EDb = ws + O_ED + (size_t)b*L_ENC*DD + d0;
    const float* H2b = ws + oH2AT + d0;
    float4 a4 = {0,0,0,0}, s4 = {0,0,0,0}, h4 = {0,0,0,0};
    for (int j = lg; j < n; j += 5){
      size_t lo = (size_t)(i0 + j)*DD;
      float wj = wl[j], hj = hl[j];
      float4 e = *(const float4*)(EAb + lo);
      a4.x += e.x*wj; a4.y += e.y*wj; a4.z += e.z*wj; a4.w += e.w*wj;
      float4 e2 = *(const float4*)(EDb + lo);
      s4.x += e2.x*wj; s4.y += e2.y*wj; s4.z += e2.z*wj; s4.w += e2.w*wj;
      float4 e3 = *(const float4*)(H2b + lo);
      h4.x += e3.x*hj; h4.y += e3.y*hj; h4.z += e3.z*hj; h4.w += e3.w*hj;
    }
    float* pp = part + (size_t)tid*12;
    *(float4*)pp = a4; *(float4*)(pp+4) = s4; *(float4*)(pp+8) = h4;
  }
  __syncthreads();
  if (tid < 96){
    float4 ra = {0,0,0,0}, rs = {0,0,0,0}, rh = {0,0,0,0};
    #pragma unroll
    for (int g = 0; g < 5; g++){
      const float* pp = part + (size_t)(g*96 + tid)*12;
      float4 pa = *(const float4*)pp, ps = *(const float4*)(pp+4), ph = *(const float4*)(pp+8);
      ra.x += pa.x; ra.y += pa.y; ra.z += pa.z; ra.w += pa.w;
      rs.x += ps.x; rs.y += ps.y; rs.z += ps.z; rs.w += ps.w;
      rh.x += ph.x; rh.y += ph.y; rh.z += ph.z; rh.w += ph.w;
    }
    int par = t & 1;
    int d0 = tid*4;
    float* A = &ws[oACTX + par*3072 + b*DD + d0];
    float* S = &ws[oSCTX + par*3072 + b*DD + d0];
    float* Pr = &ws[oPREP + par*3072 + b*DD + d0];
    atomicAdd(&A[0], ra.x); atomicAdd(&A[1], ra.y); atomicAdd(&A[2], ra.z); atomicAdd(&A[3], ra.w);
    atomicAdd(&S[0], rs.x); atomicAdd(&S[1], rs.y); atomicAdd(&S[2], rs.z); atomicAdd(&S[3], rs.w);
    atomicAdd(&Pr[0], ra.x+rh.x); atomicAdd(&Pr[1], ra.y+rh.y);
    atomicAdd(&Pr[2], ra.z+rh.z); atomicAdd(&Pr[3], ra.w+rh.w);
  }
  __syncthreads();
}

// Phase: diar GRU combine + speaker softmax + logits + loss. One block per b.
// d2a(spk_state) folded via DIB = SPK @ D2AW^T.  [R12 verbatim]
__device__ void phase_final(int b, int t, float* ws, const float* prep,
                            const DecParams& P, float* SM)
{
  float* hd_s = SM;            // 384
  float* pre_s = SM + 384;     // 384
  float* red = SM + 768;       // 512
  float* beta_s = SM + 1280;   // 8
  float* sc_s = SM + 1288;     // 8
  float* part2 = SM + 1296;    // 8*64
  int tid = threadIdx.x;
  bool act = tid < DD;
  const float* GIDp = ws + oGID; const float* GHDp = ws + oGHD;
  float* HDp = ws + oHD;
  float h = 0.f;
  if (act){
    int base = b*1152 + tid;
    float rr = sigmf(cld(&GIDp[base]) + cld(&GHDp[base]));
    float zz = sigmf(cld(&GIDp[base+384]) + cld(&GHDp[base+384]));
    float nn = tanhf(cld(&GIDp[base+768]) + rr*cld(&GHDp[base+768]));
    h = (1.f - zz)*nn + zz*cld(&HDp[b*DD + tid]);
    hd_s[tid] = h; cst(&HDp[b*DD + tid], h);
  }
  red[tid] = act ? h*h : 0.f;
  __syncthreads();
  for (int s = 256; s > 0; s >>= 1){ if (tid < s) red[tid] += red[tid+s]; __syncthreads(); }
  float hn = sqrtf(red[0]);
  int sg = tid >> 6, lane = tid & 63;
  float ps = 0.f;
  for (int j = lane; j < DD; j += 64) ps += P.SPK[((size_t)(b*8 + sg))*DD + j]*hd_s[j];
  #pragma unroll
  for (int o = 32; o > 0; o >>= 1) ps += __shfl_xor(ps, o);
  if (lane == 0) sc_s[sg] = ps / (hn * ws[oINVN + b*8 + sg]);
  __syncthreads();
  if (tid == 0){
    float mx = -1e30f;
    for (int s2 = 0; s2 < 8; s2++) mx = fmaxf(mx, sc_s[s2]);
    float sm = 0.f;
    for (int s2 = 0; s2 < 8; s2++){ float e = __expf(sc_s[s2] - mx); beta_s[s2] = e; sm += e; }
    float isv = 1.f/sm;
    for (int s2 = 0; s2 < 8; s2++) beta_s[s2] *= isv;
    int td = P.TGTD[b*T_TXT + t];
    if (td != -100){ atomicAdd(&ws[oLACC+2], beta_s[td]); atomicAdd(&ws[oLACC+3], 1.f); }
  }
  __syncthreads();
  if (tid < 8) P.out[122880 + ((size_t)(b*T_TXT + t))*8 + tid] = beta_s[tid];
  if (act){
    float p = cld(&prep[b*DD + tid]);
    const float* Mb = ws + oDIB + (size_t)(b*8)*DD + tid;
    #pragma unroll
    for (int s2 = 0; s2 < 8; s2++) p += beta_s[s2]*Mb[(size_t)s2*DD];
    pre_s[tid] = p;
  }
  __syncthreads();
  {
    int vg = tid >> 6, v = tid & 63;
    float pl = 0.f;
    if (v < VOCAB){
      const float* AOTp = ws + oAOT;
      int d0 = vg*48;
      for (int d2 = d0; d2 < d0+48; d2++) pl += pre_s[d2]*AOTp[d2*VOCAB + v];
    }
    part2[vg*64 + v] = pl;
  }
  __syncthreads();
  if (tid < VOCAB){
    float lg = P.AOB[tid];
    #pragma unroll
    for (int g = 0; g < 8; g++) lg += part2[g*64 + tid];
    P.out[((size_t)(b*T_TXT + t))*VOCAB + tid] = lg;
    int ta = P.TGTA[b*T_TXT + t];
    if (ta == tid) atomicAdd(&ws[oLACC+0], lg);
    if (tid == 0 && ta != -100) atomicAdd(&ws[oLACC+1], 1.f);
  }
  __syncthreads();
}

// Persistent decode loop (480 blocks, 2/CU), 2 barriers per step.  [R12 verbatim]
__global__ __launch_bounds__(TB, 4) void dec_loop(DecParams P)
{
  __shared__ __align__(16) float SM[17280];   // 69.1 KB
  int bid = blockIdx.x;
  float* ws = P.ws;
  unsigned* slots = (unsigned*)(ws + oBAR);
  unsigned ep = 0;

  // prologue: asr gates(0) (ACTX[par0]=HASR=0 from memset) + PREP[par0] base
  if (bid < 141)
    gates_fn<2250,750,188>(bid, ws+oWIHAT_A, ws+oWHHT_A, ws+oACTX, ws+oHASR,
                           ws+oGEA, P.ABHH, ws+oGIA, ws+oGHA, 0, SM);
  else if (bid < 149){
    int b = bid - 141;
    for (int d = threadIdx.x; d < DD; d += TB)
      cst(&ws[oPREP + b*DD + d], P.H2AB[d] + P.D2AB[d]);
  }
  gbar(slots, ++ep);

  for (int t = 0; t <= T_TXT; t++){
    // ---- Phase A ----
    if (t < T_TXT && bid < 232) phase_hattn_ctx(bid, t, ws, P, SM);
    else if (bid >= 232 && bid < 240 && t >= 1)
      phase_final(bid - 232, t - 1, ws, ws + oPREP + ((t-1) & 1)*3072, P, SM);
    gbar(slots, ++ep);
    if (t == T_TXT) break;

    // ---- Phase B ----
    if (bid < 72)
      gates_fn<1152,384,96>(bid, ws+oWIHAT_D, ws+oWHHT_D, ws+oSCTX+(t&1)*3072, ws+oHD,
                            ws+oGED, P.DBHH, ws+oGID, ws+oGHD, t, SM);
    else if (bid < 213){
      if (t + 1 < T_TXT)
        gates_fn<2250,750,188>(bid-72, ws+oWIHAT_A, ws+oWHHT_A, ws+oACTX+(t&1)*3072, ws+oHASR,
                               ws+oGEA, P.ABHH, ws+oGIA, ws+oGHA, t+1, SM);
    } else if (bid < 221 && t + 1 < T_TXT){
      int b = bid - 213, par = (t + 1) & 1;
      for (int d = threadIdx.x; d < DD; d += TB){
        cst(&ws[oACTX + par*3072 + b*DD + d], 0.f);
        cst(&ws[oSCTX + par*3072 + b*DD + d], 0.f);
        cst(&ws[oPREP + par*3072 + b*DD + d], P.H2AB[d] + P.D2AB[d]);
      }
    }
    gbar(slots, ++ep);
  }
}

__global__ void loss_final_k(const float* __restrict__ lacc, float* __restrict__ out){
  if (threadIdx.x == 0 && blockIdx.x == 0){
    float la = lacc[0]/fmaxf(lacc[1], 1.f);
    float ld = lacc[2]/fmaxf(lacc[3], 1.f);
    out[139264] = -(la + ld);
  }
}

// ---------------------------------------------------------------------------
extern "C" void kernel_launch(void* const* d_in, const int* in_sizes, int n_in,
                              void* d_out, int out_size, void* d_ws, size_t ws_size,
                              hipStream_t stream)
{
  (void)in_sizes; (void)n_in; (void)out_size; (void)ws_size;
  float* ws  = (float*)d_ws;
  float* out = (float*)d_out;

  const float* IN0   = (const float*)d_in[0];
  const float* SPK   = (const float*)d_in[1];
  const float* C1W   = (const float*)d_in[2];
  const float* C1B   = (const float*)d_in[3];
  const float* C2W   = (const float*)d_in[4];
  const float* C2B   = (const float*)d_in[5];
  const float* LAQ   = (const float*)d_in[30];
  const float* LAK   = (const float*)d_in[31];
  const float* LAV   = (const float*)d_in[32];
  const float* LAIB  = (const float*)d_in[33];
  const float* LAOW  = (const float*)d_in[34];
  const float* LAOB  = (const float*)d_in[35];
  const float* EMB   = (const float*)d_in[36];
  const float* AWIH  = (const float*)d_in[37];
  const float* AWHH  = (const float*)d_in[38];
  const float* ABIH  = (const float*)d_in[39];
  const float* ABHH  = (const float*)d_in[40];
  const float* DWIH  = (const float*)d_in[41];
  const float* DWHH  = (const float*)d_in[42];
  const float* DBIH  = (const float*)d_in[43];
  const float* DBHH  = (const float*)d_in[44];
  const float* AOW   = (const float*)d_in[45];
  const float* AOB   = (const float*)d_in[46];
  const float* D2AW  = (const float*)d_in[47];
  const float* D2AB  = (const float*)d_in[48];
  const float* H2AW  = (const float*)d_in[49];
  const float* H2AB  = (const float*)d_in[50];
  const int*   TGTA  = (const int*)d_in[51];
  const int*   TGTD  = (const int*)d_in[52];

  // encoder scratch overlay (float offsets, relative to ws)
  const size_t S_QKV = O_SCR;
  const size_t S_KT  = O_SCR + 6912000;
  const size_t S_CTX = O_SCR + 9216000;
  const size_t S_Y   = O_SCR + 11520000;
  const size_t S_H   = O_SCR + 13824000;
  const size_t X1T   = S_KT;
  const size_t Pc1   = S_H;
  const size_t Pc2   = S_QKV;

  // 1) zero decode state + loss accumulators + barrier slots/flags + zero-bias
  hipMemsetAsync((void*)(ws + O_ST), 0, 105000*sizeof(float), stream);

  // 2) convs via im2col + GEMM (conv1 K=240 -> vector; conv2 K=1152 -> MFMA)
  im2col1<<<dim3(1500,8), 256, 0, stream>>>(IN0, ws + Pc1);
  gemm_k<1,0><<<dim3(3,94), 256, 0, stream>>>(ws+Pc1, 240, C1W, 240, C1B, nullptr, ws+X1T, 384, 12000, 384, 240);
  im2col2<<<dim3(750,8), 384, 0, stream>>>(ws+X1T, ws+Pc2);
  gemm_mf<1,0><<<dim3(6,94), 256, 0, stream>>>(ws+Pc2, 1152, C2W, 1152, C2B, nullptr, ws+O_X, 384, 6000, 384, 1152);

  dup_k<<<2250, 256, 0, stream>>>(ws+O_X, ws+O_EA, ws+O_ED);

  // 3) encoder stacks (MFMA GEMMs)
  auto enc_layer = [&](float* Xb, const float* qw, const float* qb, const float* ow,
                       const float* ob, const float* f1w, const float* f1b,
                       const float* f2w, const float* f2b,
                       const float* g1, const float* b1, const float* g2, const float* b2){
    gemm_mf<0,0><<<dim3(18,94), 256, 0, stream>>>(Xb, 384, qw, 384, qb, nullptr, ws+S_QKV, 1152, 6000, 1152, 384);
    kt_k<<<dim3(3,24,32), dim3(32,8), 0, stream>>>(ws+S_QKV, ws+S_KT);
    attn_enc<<<dim3(47,4,8), 1024, 0, stream>>>(ws+S_QKV, ws+S_KT, ws+S_CTX);
    gemm_mf<0,1><<<dim3(6,94), 256, 0, stream>>>(ws+S_CTX, 384, ow, 384, ob, Xb, ws+S_Y, 384, 6000, 384, 384);
    ln_k<<<6000, 128, 0, stream>>>(ws+S_Y, g1, b1);
    gemm_mf<1,0><<<dim3(16,94), 256, 0, stream>>>(ws+S_Y, 384, f1w, 384, f1b, nullptr, ws+S_H, 1024, 6000, 1024, 384);
    gemm_mf<0,1><<<dim3(6,94), 256, 0, stream>>>(ws+S_H, 1024, f2w, 1024, f2b, ws+S_Y, Xb, 384, 6000, 384, 1024);
    ln_k<<<6000, 128, 0, stream>>>(Xb, g2, b2);
  };
  for (int st = 0; st < 2; st++){
    int base = (st == 0) ? 6 : 18;
    float* Xb = ws + ((st == 0) ? O_EA : O_ED);
    const float* qkvw = (const float*)d_in[base+0];
    const float* qkvb = (const float*)d_in[base+1];
    const float* aow  = (const float*)d_in[base+2];
    const float* aob2 = (const float*)d_in[base+3];
    const float* f1w  = (const float*)d_in[base+4];
    const float* f1b  = (const float*)d_in[base+5];
    const float* f2w  = (const float*)d_in[base+6];
    const float* f2b  = (const float*)d_in[base+7];
    const float* g1   = (const float*)d_in[base+8];
    const float* b1   = (const float*)d_in[base+9];
    const float* g2   = (const float*)d_in[base+10];
    const float* b2   = (const float*)d_in[base+11];
    for (int l = 0; l < 2; l++){
      enc_layer(Xb, qkvw + (size_t)l*1152*384, qkvb + (size_t)l*1152,
                aow + (size_t)l*384*384, aob2 + (size_t)l*384,
                f1w + (size_t)l*1024*384, f1b + (size_t)l*1024,
                f2w + (size_t)l*384*1024, f2b + (size_t)l*384,
                g1 + (size_t)l*384, b1 + (size_t)l*384, g2 + (size_t)l*384, b2 + (size_t)l*384);
    }
  }

  // 4) decode precompute (overlays encoder scratch; runs after encoder done)
  packT_k<<<dim3(12,71), dim3(32,8), 0, stream>>>(AWIH, 768, 2250, 384, ws+oWIHAT_A);
  packT_k<<<dim3(24,71), dim3(32,8), 0, stream>>>(AWHH, 750, 2250, 750, ws+oWHHT_A);
  packT_k<<<dim3(12,36), dim3(32,8), 0, stream>>>(DWIH, 768, 1152, 384, ws+oWIHAT_D);
  packT_k<<<dim3(12,36), dim3(32,8), 0, stream>>>(DWHH, 384, 1152, 384, ws+oWHHT_D);
  transpose_k<<<dim3(24,12), dim3(32,8), 0, stream>>>(H2AW, 750, 384, 750, ws+oH2AT);
  transpose_k<<<dim3(12,2),  dim3(32,8), 0, stream>>>(AOW, 384, 60, 384, ws+oAOT);
  embed_k<<<2048, 384, 0, stream>>>(EMB, TGTA, ws+oEMBT);
  gemm_mf<0,0><<<dim3(36,32), 256, 0, stream>>>(ws+oEMBT, 384, AWIH+384, 768, ABIH, nullptr, ws+oGEA, 2250, 2048, 2250, 384);
  gemm_mf<0,0><<<dim3(18,32), 256, 0, stream>>>(ws+oEMBT, 384, DWIH+384, 768, DBIH, nullptr, ws+oGED, 1152, 2048, 1152, 384);
  // DIB = SPK(64x384) @ D2AW^T -> [64][384], zero bias (tiny; vector path)
  gemm_k<0,0><<<dim3(3,1), 256, 0, stream>>>(SPK, 384, D2AW, 384, ws+oZ384, nullptr, ws+oDIB, 384, 64, 384, 384);
  vla_k<<<1500, 256, 0, stream>>>(ws+O_EA, LAV, LAIB, ws+oVLA);
  invn_k<<<64, 64, 0, stream>>>(SPK, ws+oINVN);

  // 5) persistent decode (480 blocks = 2/CU, 2 barriers/step)  [R12 config]
  DecParams DP;
  DP.ws = ws; DP.out = out;
  DP.ABHH = ABHH; DP.DBHH = DBHH; DP.SPK = SPK; DP.AOB = AOB;
  DP.LAQ = LAQ; DP.LAK = LAK; DP.LAIB = LAIB; DP.LAOW = LAOW; DP.LAOB = LAOB;
  DP.H2AB = H2AB; DP.D2AB = D2AB; DP.TGTA = TGTA; DP.TGTD = TGTD;
  dec_loop<<<dim3(NB), dim3(TB), 0, stream>>>(DP);

  loss_final_k<<<1, 64, 0, stream>>>(ws+oLACC, out);
}

// Round 14
// 19096.632 us; speedup vs baseline: 1.2085x; 1.0089x over previous
//
#include <hip/hip_runtime.h>
#include <math.h>

// ---------------------------------------------------------------------------
// Model constants
#define L_ENC 750
#define T_AUD 1500
#define DD    384
#define FF    1024
#define NHH   4
#define HDIM  96
#define VOCAB 60
#define T_TXT 256
#define BB    8
#define NB    480   // persistent decode grid: 2 blocks/CU, co-resident
#define TB    512   // decode block size (8 waves/block)

static __device__ __forceinline__ float sigmf(float x){ return 1.f/(1.f + __expf(-x)); }

// Coherent (coherence-point) accessors for mutable cross-block state.
static __device__ __forceinline__ float cld(const float* p){
  return __hip_atomic_load(p, __ATOMIC_RELAXED, __HIP_MEMORY_SCOPE_AGENT);
}
static __device__ __forceinline__ void cst(float* p, float v){
  __hip_atomic_store(p, v, __ATOMIC_RELAXED, __HIP_MEMORY_SCOPE_AGENT);
}

// bf16 <-> fp32
static __device__ __forceinline__ float bf2f(unsigned int v){
  union { unsigned int u; float f; } c; c.u = v << 16; return c.f;
}
static __device__ __forceinline__ unsigned short f2bf(float x){
  union { float f; unsigned int u; } c; c.f = x;
  unsigned int u = c.u + 0x7fffu + ((c.u >> 16) & 1u);
  return (unsigned short)(u >> 16);
}

typedef short bf16x8 __attribute__((ext_vector_type(8)));
typedef float f32x4  __attribute__((ext_vector_type(4)));

// ---------------------------------------------------------------------------
// workspace layout (float offsets)
static constexpr size_t O_X  = 0;
static constexpr size_t O_EA = 2304000;
static constexpr size_t O_ED = 4608000;
static constexpr size_t O_ST = 6912000;
static constexpr size_t oHASR = O_ST + 0;        // 6000
static constexpr size_t oATT0 = O_ST + 6000;     // 6000
static constexpr size_t oATT1 = O_ST + 12000;    // 6000
static constexpr size_t oHD   = O_ST + 18000;    // 3072 (in-place GRU)
static constexpr size_t oACTX = O_ST + 21072;    // 2 x 3072 (parity)
static constexpr size_t oSCTX = O_ST + 27216;    // 2 x 3072
static constexpr size_t oPREP = O_ST + 33360;    // 2 x 3072
static constexpr size_t oGIA  = O_ST + 39504;    // 18000
static constexpr size_t oGHA  = O_ST + 57504;    // 18000
static constexpr size_t oGID  = O_ST + 75504;    // 9216
static constexpr size_t oGHD  = O_ST + 84720;    // 9216
static constexpr size_t oLACC = O_ST + 93936;    // 8
static constexpr size_t oVLA  = O_ST + 93944;    // 6000
static constexpr size_t oINVN = O_ST + 99944;    // 64
static constexpr size_t oBAR  = O_ST + 100008;   // 4096 u32 (slots + flags)
static constexpr size_t oZ384 = O_ST + 104200;   // 384 zeros (bias for DIB gemm)
static constexpr size_t O_SCR = O_ST + 105000;
// bf16 packed gate weights [K/8][NR][8] (sizes in floats = ushorts/2)
static constexpr size_t oWIHAT_A = O_SCR + 0;         // 48*2250*8 us = 432000 f
static constexpr size_t oWHHT_A  = O_SCR + 432000;    // 94*2250*8 us = 846000 f
static constexpr size_t oWIHAT_D = O_SCR + 1278000;   // 48*1152*8 us = 221184 f
static constexpr size_t oWHHT_D  = O_SCR + 1499184;   // 48*1152*8 us = 221184 f
static constexpr size_t oH2AT    = O_SCR + 1720368;   // 750*384 f (fp32)
static constexpr size_t oAOT     = O_SCR + 2008368;   // 384*60 f
static constexpr size_t oEMBT    = O_SCR + 2031408;   // 2048*384 f
static constexpr size_t oGEA     = O_SCR + 2817840;   // 2048*2250 f
static constexpr size_t oGED     = O_SCR + 7425840;   // 2048*1152 f
static constexpr size_t oDIB     = O_SCR + 9785136;   // 64*384 f

// ---------------------------------------------------------------------------
// Generic tiled transpose: out[c*R + r] = in[r*ldin + c]
__global__ void transpose_k(const float* __restrict__ in, int ldin, int R, int C,
                            float* __restrict__ out){
  __shared__ float t[32][33];
  int c0 = blockIdx.x*32, r0 = blockIdx.y*32;
  int x = threadIdx.x, y = threadIdx.y;
  for (int i = y; i < 32; i += 8){
    int r = r0 + i, c = c0 + x;
    t[i][x] = (r < R && c < C) ? in[(size_t)r*ldin + c] : 0.f;
  }
  __syncthreads();
  for (int i = y; i < 32; i += 8){
    int c = c0 + i, r = r0 + x;
    if (c < C && r < R) out[(size_t)c*R + r] = t[x][i];
  }
}

// Pack transposed weights bf16 as [K/8][R][8]
__global__ void packTbf_k(const float* __restrict__ in, int ldin, int R, int K,
                          unsigned short* __restrict__ out){
  __shared__ float tl[32][33];
  int k0 = blockIdx.x*32, r0 = blockIdx.y*32;
  int x = threadIdx.x, y = threadIdx.y;
  int K8 = ((K + 7) >> 3) << 3;
  for (int i = y; i < 32; i += 8){
    int r = r0 + i, k = k0 + x;
    tl[i][x] = (r < R && k < K) ? in[(size_t)r*ldin + k] : 0.f;
  }
  __syncthreads();
  for (int i = y; i < 32; i += 8){
    int k = k0 + i, r = r0 + x;
    if (k < K8 && r < R) out[((size_t)(k >> 3)*R + r)*8 + (k & 7)] = f2bf(tl[x][i]);
  }
}

// K-transpose for encoder attention
__global__ void kt_k(const float* __restrict__ QKV, float* __restrict__ KT){
  __shared__ float t[32][33];
  int z = blockIdx.z; int b = z >> 2, h = z & 3;
  const float* in = QKV + (size_t)b*L_ENC*1152 + 384 + h*HDIM;
  float* out = KT + (size_t)z*HDIM*L_ENC;
  int c0 = blockIdx.x*32, r0 = blockIdx.y*32;
  int x = threadIdx.x, y = threadIdx.y;
  for (int i = y; i < 32; i += 8){
    int r = r0 + i, c = c0 + x;
    t[i][x] = (r < L_ENC && c < HDIM) ? in[(size_t)r*1152 + c] : 0.f;
  }
  __syncthreads();
  for (int i = y; i < 32; i += 8){
    int c = c0 + i, r = r0 + x;
    if (c < HDIM && r < L_ENC) out[(size_t)c*L_ENC + r] = t[x][i];
  }
}

// ---------------------------------------------------------------------------
// MFMA GEMM (bf16 inputs, fp32 accum).  K % 32 == 0.  64x64 tile, 4 waves.
template<int RELU, int HASRES>
__global__ __launch_bounds__(256) void gemm_mf(
    const float* __restrict__ A, int lda, const float* __restrict__ W, int ldw,
    const float* __restrict__ bias, const float* __restrict__ Res,
    float* __restrict__ C, int ldc, int M, int N, int K)
{
  __shared__ unsigned short Asl[64][40];   // +8 pad: 80B row stride
  __shared__ unsigned short Wsl[64][40];
  int tid = threadIdx.x;
  int row0 = blockIdx.y*64, col0 = blockIdx.x*64;
  int wv = tid >> 6, lane = tid & 63;
  f32x4 acc0 = {0,0,0,0}, acc1 = {0,0,0,0}, acc2 = {0,0,0,0}, acc3 = {0,0,0,0};
  int lr = tid & 63, lk = (tid >> 6)*8;
  int ar = row0 + lr, wr = col0 + lr;
  const float* ap = A + (size_t)ar*lda + lk;
  const float* wp = W + (size_t)wr*ldw + lk;
  int afr = wv*16 + (lane & 15);
  int bfr = lane & 15;
  int kof = (lane >> 4)*8;
  for (int k0 = 0; k0 < K; k0 += 32){
    float a8[8] = {0,0,0,0,0,0,0,0}, w8[8] = {0,0,0,0,0,0,0,0};
    if (ar < M){
      *(float4*)&a8[0] = *(const float4*)(ap + k0);
      *(float4*)&a8[4] = *(const float4*)(ap + k0 + 4);
    }
    if (wr < N){
      *(float4*)&w8[0] = *(const float4*)(wp + k0);
      *(float4*)&w8[4] = *(const float4*)(wp + k0 + 4);
    }
    __syncthreads();
    #pragma unroll
    for (int j = 0; j < 8; j++){
      Asl[lr][lk + j] = f2bf(a8[j]);
      Wsl[lr][lk + j] = f2bf(w8[j]);
    }
    __syncthreads();
    bf16x8 af = *(const bf16x8*)&Asl[afr][kof];
    bf16x8 b0 = *(const bf16x8*)&Wsl[bfr +  0][kof];
    bf16x8 b1 = *(const bf16x8*)&Wsl[bfr + 16][kof];
    bf16x8 b2 = *(const bf16x8*)&Wsl[bfr + 32][kof];
    bf16x8 b3 = *(const bf16x8*)&Wsl[bfr + 48][kof];
    acc0 = __builtin_amdgcn_mfma_f32_16x16x32_bf16(af, b0, acc0, 0, 0, 0);
    acc1 = __builtin_amdgcn_mfma_f32_16x16x32_bf16(af, b1, acc1, 0, 0, 0);
    acc2 = __builtin_amdgcn_mfma_f32_16x16x32_bf16(af, b2, acc2, 0, 0, 0);
    acc3 = __builtin_amdgcn_mfma_f32_16x16x32_bf16(af, b3, acc3, 0, 0, 0);
  }
  int crow = row0 + wv*16 + (lane >> 4)*4;
  int ccol = col0 + (lane & 15);
  f32x4 av[4] = {acc0, acc1, acc2, acc3};
  #pragma unroll
  for (int c = 0; c < 4; c++){
    int n = ccol + c*16;
    if (n >= N) continue;
    float bs = bias[n];
    #pragma unroll
    for (int j = 0; j < 4; j++){
      int m = crow + j;
      if (m >= M) continue;
      float v = av[c][j] + bs;
      if (HASRES) v += Res[(size_t)m*ldc + n];
      if (RELU) v = fmaxf(v, 0.f);
      C[(size_t)m*ldc + n] = v;
    }
  }
}

// ---------------------------------------------------------------------------
// fp32 vector GEMM, 128x128 tile (K%32 != 0 and tiny GEMMs).  K % 16 == 0.
template<int RELU, int HASRES>
__global__ __launch_bounds__(256) void gemm_k(
    const float* __restrict__ A, int lda, const float* __restrict__ W, int ldw,
    const float* __restrict__ bias, const float* __restrict__ Res,
    float* __restrict__ C, int ldc, int M, int N, int K)
{
  __shared__ __align__(16) float As[16][132];
  __shared__ __align__(16) float Ws[16][132];
  int tid = threadIdx.x;
  int row0 = blockIdx.y*128, col0 = blockIdx.x*128;
  int tx = tid & 15, ty = tid >> 4;
  int lr = tid >> 1, lk = (tid & 1)*8;
  float acc[8][8] = {};
  int ar = row0 + lr, wr = col0 + lr;
  for (int k0 = 0; k0 < K; k0 += 16){
    float4 a0 = make_float4(0,0,0,0), a1 = make_float4(0,0,0,0);
    float4 w0 = make_float4(0,0,0,0), w1 = make_float4(0,0,0,0);
    if (ar < M){
      const float* ap = A + (size_t)ar*lda + k0 + lk;
      a0 = *(const float4*)ap; a1 = *(const float4*)(ap + 4);
    }
    if (wr < N){
      const float* wp = W + (size_t)wr*ldw + k0 + lk;
      w0 = *(const float4*)wp; w1 = *(const float4*)(wp + 4);
    }
    __syncthreads();
    As[lk+0][lr] = a0.x; As[lk+1][lr] = a0.y; As[lk+2][lr] = a0.z; As[lk+3][lr] = a0.w;
    As[lk+4][lr] = a1.x; As[lk+5][lr] = a1.y; As[lk+6][lr] = a1.z; As[lk+7][lr] = a1.w;
    Ws[lk+0][lr] = w0.x; Ws[lk+1][lr] = w0.y; Ws[lk+2][lr] = w0.z; Ws[lk+3][lr] = w0.w;
    Ws[lk+4][lr] = w1.x; Ws[lk+5][lr] = w1.y; Ws[lk+6][lr] = w1.z; Ws[lk+7][lr] = w1.w;
    __syncthreads();
    #pragma unroll
    for (int k = 0; k < 16; k++){
      float av[8], bv[8];
      *(float4*)&av[0] = *(const float4*)&As[k][ty*8];
      *(float4*)&av[4] = *(const float4*)&As[k][ty*8+4];
      *(float4*)&bv[0] = *(const float4*)&Ws[k][tx*8];
      *(float4*)&bv[4] = *(const float4*)&Ws[k][tx*8+4];
      #pragma unroll
      for (int ii = 0; ii < 8; ii++){
        #pragma unroll
        for (int jj = 0; jj < 8; jj++) acc[ii][jj] += av[ii]*bv[jj];
      }
    }
  }
  #pragma unroll
  for (int ii = 0; ii < 8; ii++){
    int m = row0 + ty*8 + ii;
    if (m >= M) continue;
    #pragma unroll
    for (int jj = 0; jj < 8; jj++){
      int n = col0 + tx*8 + jj;
      if (n >= N) continue;
      float v = acc[ii][jj] + bias[n];
      if (HASRES) v += Res[(size_t)m*ldc + n];
      if (RELU) v = fmaxf(v, 0.f);
      C[(size_t)m*ldc + n] = v;
    }
  }
}

// ---------------------------------------------------------------------------
// im2col for conv1 (k=3, pad=1, stride=1)
__global__ void im2col1(const float* __restrict__ in, float* __restrict__ P){
  int t = blockIdx.x, b = blockIdx.y, i = threadIdx.x;
  if (i >= 240) return;
  int ic = i/3, kt = i - ic*3;
  int p = t + kt - 1;
  P[((size_t)(b*T_AUD + t))*240 + i] = (p >= 0 && p < T_AUD) ? in[((size_t)(b*80 + ic))*T_AUD + p] : 0.f;
}

// im2col for conv2 (k=3, pad=1, stride=2)
__global__ __launch_bounds__(384) void im2col2(const float* __restrict__ X1T, float* __restrict__ P){
  int t = blockIdx.x, b = blockIdx.y, ic = threadIdx.x;
  size_t ob = ((size_t)(b*L_ENC + t))*1152 + (size_t)ic*3;
  #pragma unroll
  for (int kt = 0; kt < 3; kt++){
    int p = 2*t + kt - 1;
    P[ob + kt] = (p >= 0 && p < T_AUD) ? X1T[((size_t)(b*T_AUD + p))*DD + ic] : 0.f;
  }
}

// Vectorized dup (rocclr D2D blit is ~serial)
__global__ __launch_bounds__(256) void dup_k(const float* __restrict__ src,
    float* __restrict__ a, float* __restrict__ b){
  size_t i = (size_t)blockIdx.x*256 + threadIdx.x;
  float4 v = ((const float4*)src)[i];
  ((float4*)a)[i] = v;
  ((float4*)b)[i] = v;
}

// ---------------------------------------------------------------------------
// LayerNorm in-place over rows of 384
__global__ __launch_bounds__(128) void ln_k(float* __restrict__ X, const float* __restrict__ g,
                                            const float* __restrict__ bt){
  int r = blockIdx.x, tid = threadIdx.x;
  float* p = X + (size_t)r*DD;
  float v0 = p[tid], v1 = p[tid+128], v2 = p[tid+256];
  __shared__ float red[128];
  red[tid] = v0+v1+v2; __syncthreads();
  for (int k = 64; k > 0; k >>= 1){ if (tid < k) red[tid] += red[tid+k]; __syncthreads(); }
  float m = red[0] * (1.f/384.f);
  __syncthreads();
  float d0 = v0-m, d1 = v1-m, d2 = v2-m;
  red[tid] = d0*d0 + d1*d1 + d2*d2; __syncthreads();
  for (int k = 64; k > 0; k >>= 1){ if (tid < k) red[tid] += red[tid+k]; __syncthreads(); }
  float rs = rsqrtf(red[0]*(1.f/384.f) + 1e-5f);
  p[tid]     = d0*rs*g[tid]     + bt[tid];
  p[tid+128] = d1*rs*g[tid+128] + bt[tid+128];
  p[tid+256] = d2*rs*g[tid+256] + bt[tid+256];
}

// ---------------------------------------------------------------------------
// Encoder attention, fused scores+softmax+AV. 16 rows per block (wave per row).
__global__ __launch_bounds__(1024) void attn_enc(const float* __restrict__ QKV,
    const float* __restrict__ KT, float* __restrict__ ctx){
  int b = blockIdx.z, h = blockIdx.y, i0 = blockIdx.x*16;
  int tid = threadIdx.x, lane = tid & 63, wv = tid >> 6;
  __shared__ float q_s[16][96];
  __shared__ float p_s[16][752];
  __shared__ float den_s[16];
  for (int idx = tid; idx < 16*96; idx += 1024){
    int r2 = idx/96, c = idx - r2*96; int i = i0 + r2;
    q_s[r2][c] = (i < L_ENC) ? QKV[((size_t)(b*L_ENC + i))*1152 + h*HDIM + c]*0.10206207f : 0.f;
  }
  __syncthreads();
  int i = i0 + wv;
  const float* ktb = KT + ((size_t)(b*4 + h))*HDIM*L_ENC;
  if (i < L_ENC){
    float sr[12] = {0,0,0,0,0,0,0,0,0,0,0,0};
    for (int c = 0; c < 96; c++){
      float qc = q_s[wv][c];
      const float* kr = ktb + c*L_ENC + lane;
      #pragma unroll
      for (int jt = 0; jt < 12; jt++) sr[jt] += qc*kr[jt*64];
    }
    float mx = -1e30f;
    #pragma unroll
    for (int jt = 0; jt < 12; jt++){ if (lane + jt*64 < L_ENC) mx = fmaxf(mx, sr[jt]); }
    #pragma unroll
    for (int o = 32; o > 0; o >>= 1) mx = fmaxf(mx, __shfl_xor(mx, o));
    float den = 0.f;
    #pragma unroll
    for (int jt = 0; jt < 12; jt++){
      int j = lane + jt*64;
      if (j < L_ENC){ float e = __expf(sr[jt]-mx); p_s[wv][j] = e; den += e; }
    }
    #pragma unroll
    for (int o = 32; o > 0; o >>= 1) den += __shfl_xor(den, o);
    if (lane == 0) den_s[wv] = den;
  }
  __syncthreads();
  if (i < L_ENC){
    float idn = 1.f/den_s[wv];
    const float* vb = QKV + (size_t)b*L_ENC*1152 + 768 + h*HDIM;
    float a0 = 0.f, a1 = 0.f;
    for (int j = 0; j < L_ENC; j++){
      float pj = p_s[wv][j];
      const float* vr = vb + (size_t)j*1152;
      a0 += pj*vr[lane];
      if (lane < 32) a1 += pj*vr[lane + 64];
    }
    size_t ob = ((size_t)(b*L_ENC + i))*DD + h*HDIM;
    ctx[ob + lane] = a0*idn;
    if (lane < 32) ctx[ob + lane + 64] = a1*idn;
  }
}

// ---------------------------------------------------------------------------
// Decode precompute helpers
__global__ __launch_bounds__(384) void embed_k(const float* __restrict__ emb,
    const int* __restrict__ tgtA, float* __restrict__ E){
  int row = blockIdx.x; int t = row >> 3, b = row & 7;
  int tok = 0;
  if (t > 0){ int v = tgtA[b*T_TXT + t - 1]; tok = (v == -100) ? 0 : v; }
  E[(size_t)row*DD + threadIdx.x] = emb[(size_t)tok*DD + threadIdx.x];
}

__global__ __launch_bounds__(256) void vla_k(const float* __restrict__ EA,
    const float* __restrict__ lav, const float* __restrict__ lain, float* __restrict__ VLA){
  int row = blockIdx.x*4 + (threadIdx.x >> 6);
  int lane = threadIdx.x & 63;
  if (row >= BB*L_ENC) return;
  const float* p = EA + (size_t)row*DD;
  float s = 0.f;
  for (int d = lane; d < DD; d += 64) s += p[d]*lav[d];
  #pragma unroll
  for (int o = 32; o > 0; o >>= 1) s += __shfl_xor(s, o);
  if (lane == 0) VLA[row] = s + lain[2];
}

__global__ void invn_k(const float* __restrict__ inv, float* __restrict__ INVN){
  int row = blockIdx.x; int lane = threadIdx.x;
  float s = 0.f;
  for (int d = lane; d < DD; d += 64){ float v = inv[(size_t)row*DD + d]; s += v*v; }
  #pragma unroll
  for (int o = 32; o > 0; o >>= 1) s += __shfl_xor(s, o);
  if (lane == 0) INVN[row] = sqrtf(s);
}

// ---------------------------------------------------------------------------
struct DecParams {
  float* ws; float* out;
  const float* ABHH; const float* DBHH;
  const float* SPK;  const float* AOB;
  const float* LAQ; const float* LAK; const float* LAIB; const float* LAOW; const float* LAOB;
  const float* H2AB; const float* D2AB;
  const int* TGTA; const int* TGTD;
};

// Grid barrier: distributed arrival slots + distributed broadcast flags.
static __device__ __forceinline__ void gbar(unsigned* s, unsigned epoch){
  __syncthreads();
  int tid = threadIdx.x;
  if (blockIdx.x == 0){
    if (tid > 0 && tid < NB){
      while (__hip_atomic_load(&s[tid*4], __ATOMIC_RELAXED, __HIP_MEMORY_SCOPE_AGENT) < epoch)
        __builtin_amdgcn_s_sleep(4);
    }
    __syncthreads();
    if (tid < NB)
      __hip_atomic_store(&s[(512 + tid)*4], epoch, __ATOMIC_RELAXED, __HIP_MEMORY_SCOPE_AGENT);
  } else {
    if (tid == 0){
      __hip_atomic_store(&s[blockIdx.x*4], epoch, __ATOMIC_RELAXED, __HIP_MEMORY_SCOPE_AGENT);
      while (__hip_atomic_load(&s[(512 + blockIdx.x)*4], __ATOMIC_RELAXED, __HIP_MEMORY_SCOPE_AGENT) < epoch)
        __builtin_amdgcn_s_sleep(4);
    }
    __syncthreads();
  }
}

// NOTE: macro params must NOT be named after vector members (w/x/y/z).
#define FMA8(acc, s_, base) { const float4 b0_ = *(const float4*)&(base)[0]; const float4 b1_ = *(const float4*)&(base)[4]; \
  acc[0]+=b0_.x*(s_); acc[1]+=b0_.y*(s_); acc[2]+=b0_.z*(s_); acc[3]+=b0_.w*(s_); \
  acc[4]+=b1_.x*(s_); acc[5]+=b1_.y*(s_); acc[6]+=b1_.z*(s_); acc[7]+=b1_.w*(s_); }

// 8 bf16 weights (uint4) against 8 consecutive k-slots of LDS ac/hh
#define GFMA8(acc, wv_, a_) { \
  FMA8(acc, bf2f(wv_.x & 0xffffu), (a_)+0);  FMA8(acc, bf2f(wv_.x >> 16), (a_)+8); \
  FMA8(acc, bf2f(wv_.y & 0xffffu), (a_)+16); FMA8(acc, bf2f(wv_.y >> 16), (a_)+24); \
  FMA8(acc, bf2f(wv_.z & 0xffffu), (a_)+32); FMA8(acc, bf2f(wv_.z >> 16), (a_)+40); \
  FMA8(acc, bf2f(wv_.w & 0xffffu), (a_)+48); FMA8(acc, bf2f(wv_.w >> 16), (a_)+56); }

// GRU gate pre-activations: one 16-row task per block, 512 thr = 32 k-parts.
// Weights bf16 packed [K/8][NR][8] -> uint4.  KOH = h-octs (asr 94, diar 48).
// [R10-verified kernel, verbatim]
template<int NR, int KH, int KOH>
__device__ void gates_fn(int task, const unsigned short* __restrict__ WIT,
                         const unsigned short* __restrict__ WHT,
                         const float* __restrict__ ctxv, const float* __restrict__ hv,
                         const float* __restrict__ GE, const float* __restrict__ bhh,
                         float* __restrict__ GI, float* __restrict__ GH, int t, float* SM)
{
  float* ac  = SM;                  // 48 octs * 64 = 3072
  float* hh  = SM + 3072;           // KOH*64
  float* pgi = SM + 3072 + KOH*64;  // [32][16][8] = 4096
  float* pgh = pgi + 4096;          // 4096
  int tid = threadIdx.x;
  for (int idx = tid; idx < 3072; idx += TB){ int b = idx/384, k = idx - b*384; ac[k*8+b] = cld(&ctxv[idx]); }
  for (int idx = tid; idx < KH*8;  idx += TB){ int b = idx/KH,  k = idx - b*KH;  hh[k*8+b] = cld(&hv[idx]); }
  for (int idx = KH*8 + tid; idx < KOH*64; idx += TB) hh[idx] = 0.f;
  __syncthreads();
  int rl = tid & 15, kp = tid >> 4;   // 32 k-partitions x 16 rows
  int r = task*16 + rl;
  float gi[8] = {}, gh[8] = {};
  if (r < NR){
    const uint4* W4 = (const uint4*)WIT;
    int q0 = (kp*48) >> 5, q1 = ((kp+1)*48) >> 5;
    for (int q = q0; q < q1; q++){
      uint4 wq = W4[(size_t)q*NR + r];
      const float* a = &ac[q*64];
      GFMA8(gi, wq, a);
    }
    const uint4* WH4 = (const uint4*)WHT;
    int h0 = (kp*KOH) >> 5, h1 = ((kp+1)*KOH) >> 5;
    for (int q = h0; q < h1; q++){
      uint4 wq = WH4[(size_t)q*NR + r];
      const float* a = &hh[q*64];
      GFMA8(gh, wq, a);
    }
  }
  #pragma unroll
  for (int b = 0; b < 8; b++){ pgi[(kp*16+rl)*8 + b] = gi[b]; pgh[(kp*16+rl)*8 + b] = gh[b]; }
  __syncthreads();
  if (tid < 128){
    int rl2 = tid & 15, bb = tid >> 4;
    int rr = task*16 + rl2;
    if (rr < NR){
      float s1 = 0.f, s2 = 0.f;
      #pragma unroll
      for (int kq = 0; kq < 32; kq++){ s1 += pgi[(kq*16+rl2)*8+bb]; s2 += pgh[(kq*16+rl2)*8+bb]; }
      cst(&GI[(size_t)bb*NR + rr], s1 + GE[((size_t)t*8 + bb)*NR + rr]);
      cst(&GH[(size_t)bb*NR + rr], s2 + bhh[rr]);
    }
  }
  __syncthreads();
}

// Phase A worker: asr GRU combine + rank-1 attention + fused ctx accumulation.
// 232 blocks, chunk-major: b = bid&7, chunk = bid>>3.  [R12 verbatim]
__device__ void phase_hattn_ctx(int bid, int t, float* ws, const DecParams& P, float* SM)
{
  float* kk = SM;            // 768
  float* vv = SM + 768;      // 768
  float* wl = SM + 1536;     // 32
  float* hl = SM + 1568;     // 32
  float* part = SM + 1600;   // 5*96*12 = 5760
  int tid = threadIdx.x;
  int b = bid & 7, chunk = bid >> 3;
  int i0 = chunk*26; int n = L_ENC - i0; if (n > 26) n = 26;
  const float* acur = ws + ((t & 1) ? oATT1 : oATT0);
  float*       anxt = ws + ((t & 1) ? oATT0 : oATT1);
  const float* GIAp = ws + oGIA; const float* GHAp = ws + oGHA;
  float* HASRp = ws + oHASR;
  const float* VLAp = ws + oVLA;
  float kw = P.LAK[0], kb = P.LAIB[1];
  for (int j = tid; j < L_ENC; j += TB){
    kk[j] = cld(&acur[b*L_ENC + j])*kw + kb;
    vv[j] = VLAp[b*L_ENC + j];
  }
  __syncthreads();
  int wv = tid >> 6, lane = tid & 63;
  float laq = P.LAQ[0], li0 = P.LAIB[0], low = P.LAOW[0], lob = P.LAOB[0];
  for (int il = wv; il < n; il += 8){
    int i = i0 + il;
    int base = b*2250 + i;
    float rr = sigmf(cld(&GIAp[base]) + cld(&GHAp[base]));
    float zz = sigmf(cld(&GIAp[base+750]) + cld(&GHAp[base+750]));
    float nn = tanhf(cld(&GIAp[base+1500]) + rr*cld(&GHAp[base+1500]));
    float h = (1.f - zz)*nn + zz*cld(&HASRp[b*L_ENC + i]);
    float q = h*laq + li0;
    float sr[12]; float mx = -1e30f;
    #pragma unroll
    for (int jt = 0; jt < 12; jt++){
      int j = lane + jt*64;
      float s = (j < L_ENC) ? q*kk[j] : -1e30f;
      sr[jt] = s; mx = fmaxf(mx, s);
    }
    #pragma unroll
    for (int o = 32; o > 0; o >>= 1) mx = fmaxf(mx, __shfl_xor(mx, o));
    float se = 0.f, sv = 0.f;
    #pragma unroll
    for (int jt = 0; jt < 12; jt++){
      int j = lane + jt*64;
      if (j < L_ENC){ float e = __expf(sr[jt] - mx); se += e; sv += e*vv[j]; }
    }
    #pragma unroll
    for (int o = 32; o > 0; o >>= 1){ se += __shfl_xor(se, o); sv += __shfl_xor(sv, o); }
    if (lane == 0){
      cst(&HASRp[b*L_ENC + i], h);
      float w = (sv/se)*low + lob;
      cst(&anxt[b*L_ENC + i], w);
      wl[il] = w; hl[il] = h;
    }
  }
  __syncthreads();
  // ctx partials: 480 threads = 5 l-groups x 96 d-quads, float4 loads
  if (tid < 480){
    int lg = tid / 96, dq = tid - lg*96;
    int d0 = dq*4;
    const float* EAb = ws + O_EA + (size_t)b*L_ENC*DD + d0;
    const float* EDb = ws + O_ED + (size_t)b*L_ENC*DD + d0;
    const float* H2b = ws + oH2AT + d0;
    float4 a4 = {0,0,0,0}, s4 = {0,0,0,0}, h4 = {0,0,0,0};
    for (int j = lg; j < n; j += 5){
      size_t lo = (size_t)(i0 + j)*DD;
      float wj = wl[j], hj = hl[j];
      float4 e = *(const float4*)(EAb + lo);
      a4.x += e.x*wj; a4.y += e.y*wj; a4.z += e.z*wj; a4.w += e.w*wj;
      float4 e2 = *(const float4*)(EDb + lo);
      s4.x += e2.x*wj; s4.y += e2.y*wj; s4.z += e2.z*wj; s4.w += e2.w*wj;
      float4 e3 = *(const float4*)(H2b + lo);
      h4.x += e3.x*hj; h4.y += e3.y*hj; h4.z += e3.z*hj; h4.w += e3.w*hj;
    }
    float* pp = part + (size_t)tid*12;
    *(float4*)pp = a4; *(float4*)(pp+4) = s4; *(float4*)(pp+8) = h4;
  }
  __syncthreads();
  if (tid < 96){
    float4 ra = {0,0,0,0}, rs = {0,0,0,0}, rh = {0,0,0,0};
    #pragma unroll
    for (int g = 0; g < 5; g++){
      const float* pp = part + (size_t)(g*96 + tid)*12;
      float4 pa = *(const float4*)pp, ps = *(const float4*)(pp+4), ph = *(const float4*)(pp+8);
      ra.x += pa.x; ra.y += pa.y; ra.z += pa.z; ra.w += pa.w;
      rs.x += ps.x; rs.y += ps.y; rs.z += ps.z; rs.w += ps.w;
      rh.x += ph.x; rh.y += ph.y; rh.z += ph.z; rh.w += ph.w;
    }
    int par = t & 1;
    int d0 = tid*4;
    float* A = &ws[oACTX + par*3072 + b*DD + d0];
    float* S = &ws[oSCTX + par*3072 + b*DD + d0];
    float* Pr = &ws[oPREP + par*3072 + b*DD + d0];
    atomicAdd(&A[0], ra.x); atomicAdd(&A[1], ra.y); atomicAdd(&A[2], ra.z); atomicAdd(&A[3], ra.w);
    atomicAdd(&S[0], rs.x); atomicAdd(&S[1], rs.y); atomicAdd(&S[2], rs.z); atomicAdd(&S[3], rs.w);
    atomicAdd(&Pr[0], ra.x+rh.x); atomicAdd(&Pr[1], ra.y+rh.y);
    atomicAdd(&Pr[2], ra.z+rh.z); atomicAdd(&Pr[3], ra.w+rh.w);
  }
  __syncthreads();
}

// Phase: diar GRU combine + speaker softmax + logits + loss. One block per b.
// [R12 verbatim]
__device__ void phase_final(int b, int t, float* ws, const float* prep,
                            const DecParams& P, float* SM)
{
  float* hd_s = SM;            // 384
  float* pre_s = SM + 384;     // 384
  float* red = SM + 768;       // 512
  float* beta_s = SM + 1280;   // 8
  float* sc_s = SM + 1288;     // 8
  float* part2 = SM + 1296;    // 8*64
  int tid = threadIdx.x;
  bool act = tid < DD;
  const float* GIDp = ws + oGID; const float* GHDp = ws + oGHD;
  float* HDp = ws + oHD;
  float h = 0.f;
  if (act){
    int base = b*1152 + tid;
    float rr = sigmf(cld(&GIDp[base]) + cld(&GHDp[base]));
    float zz = sigmf(cld(&GIDp[base+384]) + cld(&GHDp[base+384]));
    float nn = tanhf(cld(&GIDp[base+768]) + rr*cld(&GHDp[base+768]));
    h = (1.f - zz)*nn + zz*cld(&HDp[b*DD + tid]);
    hd_s[tid] = h; cst(&HDp[b*DD + tid], h);
  }
  red[tid] = act ? h*h : 0.f;
  __syncthreads();
  for (int s = 256; s > 0; s >>= 1){ if (tid < s) red[tid] += red[tid+s]; __syncthreads(); }
  float hn = sqrtf(red[0]);
  int sg = tid >> 6, lane = tid & 63;
  float ps = 0.f;
  for (int j = lane; j < DD; j += 64) ps += P.SPK[((size_t)(b*8 + sg))*DD + j]*hd_s[j];
  #pragma unroll
  for (int o = 32; o > 0; o >>= 1) ps += __shfl_xor(ps, o);
  if (lane == 0) sc_s[sg] = ps / (hn * ws[oINVN + b*8 + sg]);
  __syncthreads();
  if (tid == 0){
    float mx = -1e30f;
    for (int s2 = 0; s2 < 8; s2++) mx = fmaxf(mx, sc_s[s2]);
    float sm = 0.f;
    for (int s2 = 0; s2 < 8; s2++){ float e = __expf(sc_s[s2] - mx); beta_s[s2] = e; sm += e; }
    float isv = 1.f/sm;
    for (int s2 = 0; s2 < 8; s2++) beta_s[s2] *= isv;
    int td = P.TGTD[b*T_TXT + t];
    if (td != -100){ atomicAdd(&ws[oLACC+2], beta_s[td]); atomicAdd(&ws[oLACC+3], 1.f); }
  }
  __syncthreads();
  if (tid < 8) P.out[122880 + ((size_t)(b*T_TXT + t))*8 + tid] = beta_s[tid];
  if (act){
    float p = cld(&prep[b*DD + tid]);
    const float* Mb = ws + oDIB + (size_t)(b*8)*DD + tid;
    #pragma unroll
    for (int s2 = 0; s2 < 8; s2++) p += beta_s[s2]*Mb[(size_t)s2*DD];
    pre_s[tid] = p;
  }
  __syncthreads();
  {
    int vg = tid >> 6, v = tid & 63;
    float pl = 0.f;
    if (v < VOCAB){
      const float* AOTp = ws + oAOT;
      int d0 = vg*48;
      for (int d2 = d0; d2 < d0+48; d2++) pl += pre_s[d2]*AOTp[d2*VOCAB + v];
    }
    part2[vg*64 + v] = pl;
  }
  __syncthreads();
  if (tid < VOCAB){
    float lg = P.AOB[tid];
    #pragma unroll
    for (int g = 0; g < 8; g++) lg += part2[g*64 + tid];
    P.out[((size_t)(b*T_TXT + t))*VOCAB + tid] = lg;
    int ta = P.TGTA[b*T_TXT + t];
    if (ta == tid) atomicAdd(&ws[oLACC+0], lg);
    if (tid == 0 && ta != -100) atomicAdd(&ws[oLACC+1], 1.f);
  }
  __syncthreads();
}

// Persistent decode loop (480 blocks, 2/CU), 2 barriers per step.
// A: hattn+ctx(t)[0..231] || final(t-1)[232..239]
// B: gates_D(t)[0..71] || gates_A(t+1)[72..212] || init(t+1)[213..220]
__global__ __launch_bounds__(TB, 4) void dec_loop(DecParams P)
{
  __shared__ __align__(16) float SM[17280];   // 69.1 KB
  int bid = blockIdx.x;
  float* ws = P.ws;
  unsigned* slots = (unsigned*)(ws + oBAR);
  unsigned ep = 0;
  const unsigned short* WIA = (const unsigned short*)(ws + oWIHAT_A);
  const unsigned short* WHA = (const unsigned short*)(ws + oWHHT_A);
  const unsigned short* WID = (const unsigned short*)(ws + oWIHAT_D);
  const unsigned short* WHD = (const unsigned short*)(ws + oWHHT_D);

  // prologue: asr gates(0) (ACTX[par0]=HASR=0 from memset) + PREP[par0] base
  if (bid < 141)
    gates_fn<2250,750,94>(bid, WIA, WHA, ws+oACTX, ws+oHASR,
                          ws+oGEA, P.ABHH, ws+oGIA, ws+oGHA, 0, SM);
  else if (bid < 149){
    int b = bid - 141;
    for (int d = threadIdx.x; d < DD; d += TB)
      cst(&ws[oPREP + b*DD + d], P.H2AB[d] + P.D2AB[d]);
  }
  gbar(slots, ++ep);

  for (int t = 0; t <= T_TXT; t++){
    // ---- Phase A ----
    if (t < T_TXT && bid < 232) phase_hattn_ctx(bid, t, ws, P, SM);
    else if (bid >= 232 && bid < 240 && t >= 1)
      phase_final(bid - 232, t - 1, ws, ws + oPREP + ((t-1) & 1)*3072, P, SM);
    gbar(slots, ++ep);
    if (t == T_TXT) break;

    // ---- Phase B ----
    if (bid < 72)
      gates_fn<1152,384,48>(bid, WID, WHD, ws+oSCTX+(t&1)*3072, ws+oHD,
                            ws+oGED, P.DBHH, ws+oGID, ws+oGHD, t, SM);
    else if (bid < 213){
      if (t + 1 < T_TXT)
        gates_fn<2250,750,94>(bid-72, WIA, WHA, ws+oACTX+(t&1)*3072, ws+oHASR,
                              ws+oGEA, P.ABHH, ws+oGIA, ws+oGHA, t+1, SM);
    } else if (bid < 221 && t + 1 < T_TXT){
      int b = bid - 213, par = (t + 1) & 1;
      for (int d = threadIdx.x; d < DD; d += TB){
        cst(&ws[oACTX + par*3072 + b*DD + d], 0.f);
        cst(&ws[oSCTX + par*3072 + b*DD + d], 0.f);
        cst(&ws[oPREP + par*3072 + b*DD + d], P.H2AB[d] + P.D2AB[d]);
      }
    }
    gbar(slots, ++ep);
  }
}

__global__ void loss_final_k(const float* __restrict__ lacc, float* __restrict__ out){
  if (threadIdx.x == 0 && blockIdx.x == 0){
    float la = lacc[0]/fmaxf(lacc[1], 1.f);
    float ld = lacc[2]/fmaxf(lacc[3], 1.f);
    out[139264] = -(la + ld);
  }
}

// ---------------------------------------------------------------------------
extern "C" void kernel_launch(void* const* d_in, const int* in_sizes, int n_in,
                              void* d_out, int out_size, void* d_ws, size_t ws_size,
                              hipStream_t stream)
{
  (void)in_sizes; (void)n_in; (void)out_size; (void)ws_size;
  float* ws  = (float*)d_ws;
  float* out = (float*)d_out;

  const float* IN0   = (const float*)d_in[0];
  const float* SPK   = (const float*)d_in[1];
  const float* C1W   = (const float*)d_in[2];
  const float* C1B   = (const float*)d_in[3];
  const float* C2W   = (const float*)d_in[4];
  const float* C2B   = (const float*)d_in[5];
  const float* LAQ   = (const float*)d_in[30];
  const float* LAK   = (const float*)d_in[31];
  const float* LAV   = (const float*)d_in[32];
  const float* LAIB  = (const float*)d_in[33];
  const float* LAOW  = (const float*)d_in[34];
  const float* LAOB  = (const float*)d_in[35];
  const float* EMB   = (const float*)d_in[36];
  const float* AWIH  = (const float*)d_in[37];
  const float* AWHH  = (const float*)d_in[38];
  const float* ABIH  = (const float*)d_in[39];
  const float* ABHH  = (const float*)d_in[40];
  const float* DWIH  = (const float*)d_in[41];
  const float* DWHH  = (const float*)d_in[42];
  const float* DBIH  = (const float*)d_in[43];
  const float* DBHH  = (const float*)d_in[44];
  const float* AOW   = (const float*)d_in[45];
  const float* AOB   = (const float*)d_in[46];
  const float* D2AW  = (const float*)d_in[47];
  const float* D2AB  = (const float*)d_in[48];
  const float* H2AW  = (const float*)d_in[49];
  const float* H2AB  = (const float*)d_in[50];
  const int*   TGTA  = (const int*)d_in[51];
  const int*   TGTD  = (const int*)d_in[52];

  // encoder scratch overlay (float offsets, relative to ws)
  const size_t S_QKV = O_SCR;
  const size_t S_KT  = O_SCR + 6912000;
  const size_t S_CTX = O_SCR + 9216000;
  const size_t S_Y   = O_SCR + 11520000;
  const size_t S_H   = O_SCR + 13824000;
  const size_t X1T   = S_KT;
  const size_t Pc1   = S_H;
  const size_t Pc2   = S_QKV;

  // 1) zero decode state + loss accumulators + barrier slots/flags + zero-bias
  hipMemsetAsync((void*)(ws + O_ST), 0, 105000*sizeof(float), stream);

  // 2) convs via im2col + GEMM (conv1 K=240 -> vector; conv2 K=1152 -> MFMA)
  im2col1<<<dim3(1500,8), 256, 0, stream>>>(IN0, ws + Pc1);
  gemm_k<1,0><<<dim3(3,94), 256, 0, stream>>>(ws+Pc1, 240, C1W, 240, C1B, nullptr, ws+X1T, 384, 12000, 384, 240);
  im2col2<<<dim3(750,8), 384, 0, stream>>>(ws+X1T, ws+Pc2);
  gemm_mf<1,0><<<dim3(6,94), 256, 0, stream>>>(ws+Pc2, 1152, C2W, 1152, C2B, nullptr, ws+O_X, 384, 6000, 384, 1152);

  dup_k<<<2250, 256, 0, stream>>>(ws+O_X, ws+O_EA, ws+O_ED);

  // 3) encoder stacks (MFMA GEMMs)
  auto enc_layer = [&](float* Xb, const float* qw, const float* qb, const float* ow,
                       const float* ob, const float* f1w, const float* f1b,
                       const float* f2w, const float* f2b,
                       const float* g1, const float* b1, const float* g2, const float* b2){
    gemm_mf<0,0><<<dim3(18,94), 256, 0, stream>>>(Xb, 384, qw, 384, qb, nullptr, ws+S_QKV, 1152, 6000, 1152, 384);
    kt_k<<<dim3(3,24,32), dim3(32,8), 0, stream>>>(ws+S_QKV, ws+S_KT);
    attn_enc<<<dim3(47,4,8), 1024, 0, stream>>>(ws+S_QKV, ws+S_KT, ws+S_CTX);
    gemm_mf<0,1><<<dim3(6,94), 256, 0, stream>>>(ws+S_CTX, 384, ow, 384, ob, Xb, ws+S_Y, 384, 6000, 384, 384);
    ln_k<<<6000, 128, 0, stream>>>(ws+S_Y, g1, b1);
    gemm_mf<1,0><<<dim3(16,94), 256, 0, stream>>>(ws+S_Y, 384, f1w, 384, f1b, nullptr, ws+S_H, 1024, 6000, 1024, 384);
    gemm_mf<0,1><<<dim3(6,94), 256, 0, stream>>>(ws+S_H, 1024, f2w, 1024, f2b, ws+S_Y, Xb, 384, 6000, 384, 1024);
    ln_k<<<6000, 128, 0, stream>>>(Xb, g2, b2);
  };
  for (int st = 0; st < 2; st++){
    int base = (st == 0) ? 6 : 18;
    float* Xb = ws + ((st == 0) ? O_EA : O_ED);
    const float* qkvw = (const float*)d_in[base+0];
    const float* qkvb = (const float*)d_in[base+1];
    const float* aow  = (const float*)d_in[base+2];
    const float* aob2 = (const float*)d_in[base+3];
    const float* f1w  = (const float*)d_in[base+4];
    const float* f1b  = (const float*)d_in[base+5];
    const float* f2w  = (const float*)d_in[base+6];
    const float* f2b  = (const float*)d_in[base+7];
    const float* g1   = (const float*)d_in[base+8];
    const float* b1   = (const float*)d_in[base+9];
    const float* g2   = (const float*)d_in[base+10];
    const float* b2   = (const float*)d_in[base+11];
    for (int l = 0; l < 2; l++){
      enc_layer(Xb, qkvw + (size_t)l*1152*384, qkvb + (size_t)l*1152,
                aow + (size_t)l*384*384, aob2 + (size_t)l*384,
                f1w + (size_t)l*1024*384, f1b + (size_t)l*1024,
                f2w + (size_t)l*384*1024, f2b + (size_t)l*384,
                g1 + (size_t)l*384, b1 + (size_t)l*384, g2 + (size_t)l*384, b2 + (size_t)l*384);
    }
  }

  // 4) decode precompute (overlays encoder scratch; runs after encoder done)
  packTbf_k<<<dim3(12,71), dim3(32,8), 0, stream>>>(AWIH, 768, 2250, 384, (unsigned short*)(ws+oWIHAT_A));
  packTbf_k<<<dim3(24,71), dim3(32,8), 0, stream>>>(AWHH, 750, 2250, 750, (unsigned short*)(ws+oWHHT_A));
  packTbf_k<<<dim3(12,36), dim3(32,8), 0, stream>>>(DWIH, 768, 1152, 384, (unsigned short*)(ws+oWIHAT_D));
  packTbf_k<<<dim3(12,36), dim3(32,8), 0, stream>>>(DWHH, 384, 1152, 384, (unsigned short*)(ws+oWHHT_D));
  transpose_k<<<dim3(24,12), dim3(32,8), 0, stream>>>(H2AW, 750, 384, 750, ws+oH2AT);
  transpose_k<<<dim3(12,2),  dim3(32,8), 0, stream>>>(AOW, 384, 60, 384, ws+oAOT);
  embed_k<<<2048, 384, 0, stream>>>(EMB, TGTA, ws+oEMBT);
  gemm_mf<0,0><<<dim3(36,32), 256, 0, stream>>>(ws+oEMBT, 384, AWIH+384, 768, ABIH, nullptr, ws+oGEA, 2250, 2048, 2250, 384);
  gemm_mf<0,0><<<dim3(18,32), 256, 0, stream>>>(ws+oEMBT, 384, DWIH+384, 768, DBIH, nullptr, ws+oGED, 1152, 2048, 1152, 384);
  // DIB = SPK(64x384) @ D2AW^T -> [64][384], zero bias (tiny; vector path)
  gemm_k<0,0><<<dim3(3,1), 256, 0, stream>>>(SPK, 384, D2AW, 384, ws+oZ384, nullptr, ws+oDIB, 384, 64, 384, 384);
  vla_k<<<1500, 256, 0, stream>>>(ws+O_EA, LAV, LAIB, ws+oVLA);
  invn_k<<<64, 64, 0, stream>>>(SPK, ws+oINVN);

  // 5) persistent decode (480 blocks = 2/CU, 2 barriers/step, bf16 gate weights)
  DecParams DP;
  DP.ws = ws; DP.out = out;
  DP.ABHH = ABHH; DP.DBHH = DBHH; DP.SPK = SPK; DP.AOB = AOB;
  DP.LAQ = LAQ; DP.LAK = LAK; DP.LAIB = LAIB; DP.LAOW = LAOW; DP.LAOB = LAOB;
  DP.H2AB = H2AB; DP.D2AB = D2AB; DP.TGTA = TGTA; DP.TGTD = TGTD;
  dec_loop<<<dim3(NB), dim3(TB), 0, stream>>>(DP);

  loss_final_k<<<1, 64, 0, stream>>>(ws+oLACC, out);
}